// Round 1
// baseline (3754.630 us; speedup 1.0000x reference)
//
#include <hip/hip_runtime.h>
#include <cstdint>
#include <cstddef>

#define NEG_SLOPE 0.2f
#define BN_EPS 1e-5f

// ---------- float <-> order-preserving uint (for atomicMax on float) ----------
__device__ __forceinline__ unsigned int fflip(float f) {
    unsigned int u = __float_as_uint(f);
    return (u & 0x80000000u) ? ~u : (u | 0x80000000u);
}
__device__ __forceinline__ float funflip(unsigned int u) {
    return __uint_as_float((u & 0x80000000u) ? (u & 0x7FFFFFFFu) : ~u);
}

// ---------- fp32 tiled GEMM: C[M,Ncol] = (A (+A2)) @ B, all row-major ----------
#define BM 64
#define BN 64
#define BK 16
__global__ __launch_bounds__(256) void gemm_f32(
    const float* __restrict__ A, const float* __restrict__ A2,
    const float* __restrict__ B, float* __restrict__ C,
    int M, int K, int Ncol) {
    __shared__ float As[BK][BM + 2];   // +2 pad: conflict-free transposed store
    __shared__ float Bs[BK][BN];
    const int tid = threadIdx.x;
    const int tx = tid & 15;           // 16 thread-cols
    const int ty = tid >> 4;           // 16 thread-rows
    const int row0 = blockIdx.y * BM;
    const int col0 = blockIdx.x * BN;
    float acc[4][4] = {};

    for (int k0 = 0; k0 < K; k0 += BK) {
        // A tile: 64 rows x 16 k, stored transposed As[k][m]
        #pragma unroll
        for (int i = 0; i < 4; ++i) {
            int r  = (tid >> 4) + i * 16;   // 0..63
            int kk = tid & 15;
            int grow = row0 + r, gk = k0 + kk;
            float v = 0.f;
            if (grow < M && gk < K) {
                v = A[(size_t)grow * K + gk];
                if (A2) v += A2[(size_t)grow * K + gk];
            }
            As[kk][r] = v;
        }
        // B tile: 16 k x 64 cols
        #pragma unroll
        for (int i = 0; i < 4; ++i) {
            int kk = (tid >> 6) + i * 4;    // 0..15
            int c  = tid & 63;
            int gk = k0 + kk;
            float v = 0.f;
            if (gk < K) v = B[(size_t)gk * Ncol + col0 + c];
            Bs[kk][c] = v;
        }
        __syncthreads();
        #pragma unroll
        for (int kk = 0; kk < BK; ++kk) {
            float a[4], b[4];
            #pragma unroll
            for (int i = 0; i < 4; ++i) a[i] = As[kk][ty * 4 + i];
            #pragma unroll
            for (int j = 0; j < 4; ++j) b[j] = Bs[kk][tx * 4 + j];
            #pragma unroll
            for (int i = 0; i < 4; ++i)
                #pragma unroll
                for (int j = 0; j < 4; ++j)
                    acc[i][j] = fmaf(a[i], b[j], acc[i][j]);
        }
        __syncthreads();
    }
    #pragma unroll
    for (int i = 0; i < 4; ++i) {
        int r = row0 + ty * 4 + i;
        if (r < M) {
            #pragma unroll
            for (int j = 0; j < 4; ++j)
                C[(size_t)r * Ncol + col0 + tx * 4 + j] = acc[i][j];
        }
    }
}

// ---------- per-node attention logits: alpha_s/d[n,h] = sum_c h[n,h,c]*a[h,c] ----------
__global__ void alpha_kernel(const float* __restrict__ h,
                             const float* __restrict__ avs, const float* __restrict__ avd,
                             float* __restrict__ alpha_s, float* __restrict__ alpha_d,
                             int HEADS, int C) {
    const int n = blockIdx.x;
    const int t = threadIdx.x;
    const int D = HEADS * C;
    __shared__ float ss[256], sd[256];
    float vs = 0.f, vd = 0.f;
    if (t < D) {
        float v = h[(size_t)n * D + t];
        vs = v * avs[t];
        vd = v * avd[t];
    }
    ss[t] = vs; sd[t] = vd;
    __syncthreads();
    if (t < HEADS) {
        float as_ = 0.f, ad_ = 0.f;
        for (int c = 0; c < C; ++c) { as_ += ss[t * C + c]; ad_ += sd[t * C + c]; }
        alpha_s[n * HEADS + t] = as_;
        alpha_d[n * HEADS + t] = ad_;
    }
}

// ---------- edge pass 1: segment max over dst ----------
__global__ void edge_max_kernel(const int* __restrict__ ei,
                                const float* __restrict__ asrc, const float* __restrict__ adst,
                                unsigned int* __restrict__ mflip,
                                int E, int Etot, int HEADS) {
    int idx = blockIdx.x * blockDim.x + threadIdx.x;
    if (idx >= Etot * HEADS) return;
    int e = idx / HEADS, hd = idx - e * HEADS;
    int s, d;
    if (e < E) { s = ei[e]; d = ei[E + e]; } else { s = e - E; d = s; }
    float v = asrc[s * HEADS + hd] + adst[d * HEADS + hd];
    v = v > 0.f ? v : NEG_SLOPE * v;
    atomicMax(&mflip[d * HEADS + hd], fflip(v));
}

// ---------- edge pass 2: p = exp(e - m[dst]); denom[dst] += p ----------
__global__ void edge_exp_kernel(const int* __restrict__ ei,
                                const float* __restrict__ asrc, const float* __restrict__ adst,
                                const unsigned int* __restrict__ mflip,
                                float* __restrict__ denom, float* __restrict__ pbuf,
                                int E, int Etot, int HEADS) {
    int idx = blockIdx.x * blockDim.x + threadIdx.x;
    if (idx >= Etot * HEADS) return;
    int e = idx / HEADS, hd = idx - e * HEADS;
    int s, d;
    if (e < E) { s = ei[e]; d = ei[E + e]; } else { s = e - E; d = s; }
    float v = asrc[s * HEADS + hd] + adst[d * HEADS + hd];
    v = v > 0.f ? v : NEG_SLOPE * v;
    float m = funflip(mflip[d * HEADS + hd]);
    float p = expf(v - m);
    pbuf[idx] = p;
    atomicAdd(&denom[d * HEADS + hd], p);
}

// ---------- edge pass 3: out[dst] += h[src] * alpha  (block = D threads, 1 edge/block) ----------
__global__ void edge_agg_kernel(const int* __restrict__ ei, const float* __restrict__ h,
                                const float* __restrict__ pbuf, const float* __restrict__ denom,
                                float* __restrict__ out,
                                int E, int HEADS, int logC) {
    const int e = blockIdx.x;
    const int t = threadIdx.x;
    const int D = blockDim.x;
    int s, d;
    if (e < E) { s = ei[e]; d = ei[E + e]; } else { s = e - E; d = s; }
    const int hd = t >> logC;
    float alpha = pbuf[(size_t)e * HEADS + hd] / (denom[d * HEADS + hd] + 1e-16f);
    atomicAdd(&out[(size_t)d * D + t], h[(size_t)s * D + t] * alpha);
}

// ---------- bias + BN(inference) + ReLU, in place ----------
__global__ void bn_relu_kernel(float* __restrict__ io, const float* __restrict__ bias,
                               const float* __restrict__ gamma, const float* __restrict__ beta,
                               const float* __restrict__ mean, const float* __restrict__ var,
                               int total, int Dmask) {
    int i = blockIdx.x * blockDim.x + threadIdx.x;
    if (i >= total) return;
    int j = i & Dmask;
    float v = io[i] + bias[j];
    v = (v - mean[j]) * rsqrtf(var[j] + BN_EPS) * gamma[j] + beta[j];
    io[i] = fmaxf(v, 0.f);
}

// ---------- pooling gate: gate[n] = relu(x4@pw1+pb1)@pw2+pb2; per-graph atomicMax ----------
__global__ void gate_kernel(const float* __restrict__ x4,
                            const float* __restrict__ pw1, const float* __restrict__ pb1,
                            const float* __restrict__ pw2, const float* __restrict__ pb2,
                            const int* __restrict__ batch,
                            float* __restrict__ gate, unsigned int* __restrict__ gmaxf) {
    const int n = blockIdx.x;
    const int lane = threadIdx.x;   // block 64
    float t = 0.f;
    if (lane < 32) {
        float acc = pb1[lane];
        #pragma unroll 4
        for (int c = 0; c < 128; ++c) acc = fmaf(x4[(size_t)n * 128 + c], pw1[c * 32 + lane], acc);
        t = fmaxf(acc, 0.f) * pw2[lane];
    }
    #pragma unroll
    for (int o = 32; o > 0; o >>= 1) t += __shfl_down(t, o, 64);
    if (lane == 0) {
        float gv = t + pb2[0];
        gate[n] = gv;
        atomicMax(&gmaxf[batch[n]], fflip(gv));
    }
}

__global__ void gate_exp_kernel(const float* __restrict__ gate,
                                const unsigned int* __restrict__ gmaxf,
                                const int* __restrict__ batch,
                                float* __restrict__ gexp, float* __restrict__ gden, int N) {
    int n = blockIdx.x * blockDim.x + threadIdx.x;
    if (n >= N) return;
    int b = batch[n];
    float ge = expf(gate[n] - funflip(gmaxf[b]));
    gexp[n] = ge;
    atomicAdd(&gden[b], ge);
}

// ---------- weighted pooling into d_out[:, 0:128] ----------
__global__ void pool_agg_kernel(const float* __restrict__ x4, const float* __restrict__ gexp,
                                const float* __restrict__ gden, const int* __restrict__ batch,
                                float* __restrict__ out) {
    const int n = blockIdx.x;
    const int c = threadIdx.x;      // block 128
    const int b = batch[n];
    float attn = gexp[n] / (gden[b] + 1e-16f);
    atomicAdd(&out[(size_t)b * 160 + c], attn * x4[(size_t)n * 128 + c]);
}

// ---------- global-feature MLP into d_out[:, 128:160] ----------
__global__ void gfeat_kernel(const float* __restrict__ gfeat,
                             const float* __restrict__ gw, const float* __restrict__ gb,
                             float* __restrict__ out) {
    const int g = blockIdx.x;
    const int k = threadIdx.x;      // block 64, first 32 active
    if (k < 32) {
        float t = gb[k];
        #pragma unroll
        for (int j = 0; j < 7; ++j) t = fmaf(gfeat[g * 7 + j], gw[j * 32 + k], t);
        out[(size_t)g * 160 + 128 + k] = fmaxf(t, 0.f);
    }
}

// ==========================================================================
extern "C" void kernel_launch(void* const* d_in, const int* in_sizes, int n_in,
                              void* d_out, int out_size, void* d_ws, size_t ws_size,
                              hipStream_t stream) {
    const float* x      = (const float*)d_in[0];
    const int*   ei     = (const int*)  d_in[1];
    const int*   batch  = (const int*)  d_in[2];
    const float* gfeat  = (const float*)d_in[3];

    const int N    = in_sizes[2];
    const int E    = in_sizes[1] / 2;
    const int G    = in_sizes[3] / 7;
    const int IN   = in_sizes[0] / N;
    const int Etot = E + N;

    // per-layer params: idx 4 + 8*(l-1): W, as, ad, b, g, be, m, v
    const float* W[4];  const float* avs[4]; const float* avd[4]; const float* bi[4];
    const float* ga[4]; const float* be[4];  const float* mu[4];  const float* va[4];
    for (int l = 0; l < 4; ++l) {
        int o = 4 + 8 * l;
        W[l]   = (const float*)d_in[o + 0];
        avs[l] = (const float*)d_in[o + 1];
        avd[l] = (const float*)d_in[o + 2];
        bi[l]  = (const float*)d_in[o + 3];
        ga[l]  = (const float*)d_in[o + 4];
        be[l]  = (const float*)d_in[o + 5];
        mu[l]  = (const float*)d_in[o + 6];
        va[l]  = (const float*)d_in[o + 7];
    }
    const float* pw1 = (const float*)d_in[36];
    const float* pb1 = (const float*)d_in[37];
    const float* pw2 = (const float*)d_in[38];
    const float* pb2 = (const float*)d_in[39];
    const float* gw  = (const float*)d_in[40];
    const float* gb  = (const float*)d_in[41];

    float* out = (float*)d_out;

    // ---- workspace carve-up (floats) ----
    float* ws = (float*)d_ws;
    float* h    = ws;  ws += (size_t)N * 256;
    float* x1   = ws;  ws += (size_t)N * 256;
    float* x2   = ws;  ws += (size_t)N * 256;
    float* x3   = ws;  ws += (size_t)N * 256;
    float* asrc = ws;  ws += (size_t)N * 4;
    float* adst = ws;  ws += (size_t)N * 4;
    unsigned int* mflip = (unsigned int*)ws; ws += (size_t)N * 4;
    float* denom = ws; ws += (size_t)N * 4;
    float* pbuf  = ws; ws += (size_t)Etot * 4;
    float* gate  = ws; ws += N;
    float* gexp  = ws; ws += N;
    unsigned int* gmaxf = (unsigned int*)ws; ws += G;
    float* gden  = ws; ws += G;
    float* x4 = x1;    // x1 is dead after the layer-3 GEMM; reuse for x4 [N,128]

    auto run_layer = [&](const float* A, const float* A2, int K, int HEADS, int C, int l,
                         float* xout) {
        const int D = HEADS * C;
        const int logC = (C == 64) ? 6 : 7;
        // 1. h = (A (+A2)) @ W
        dim3 ggrid(D / BN, (N + BM - 1) / BM);
        hipLaunchKernelGGL(gemm_f32, ggrid, dim3(256), 0, stream, A, A2, W[l], h, N, K, D);
        // 2. attention logits
        hipLaunchKernelGGL(alpha_kernel, dim3(N), dim3(256), 0, stream,
                           h, avs[l], avd[l], asrc, adst, HEADS, C);
        // 3. zero accumulators (flip-space 0 < flip(x) for every real x -> acts as -inf)
        hipMemsetAsync(mflip, 0, (size_t)N * HEADS * 4, stream);
        hipMemsetAsync(denom, 0, (size_t)N * HEADS * 4, stream);
        hipMemsetAsync(xout,  0, (size_t)N * D * 4, stream);
        // 4-6. edge passes
        int tE = Etot * HEADS;
        hipLaunchKernelGGL(edge_max_kernel, dim3((tE + 255) / 256), dim3(256), 0, stream,
                           ei, asrc, adst, mflip, E, Etot, HEADS);
        hipLaunchKernelGGL(edge_exp_kernel, dim3((tE + 255) / 256), dim3(256), 0, stream,
                           ei, asrc, adst, mflip, denom, pbuf, E, Etot, HEADS);
        hipLaunchKernelGGL(edge_agg_kernel, dim3(Etot), dim3(D), 0, stream,
                           ei, h, pbuf, denom, xout, E, HEADS, logC);
        // 7. bias + BN + ReLU
        int total = N * D;
        hipLaunchKernelGGL(bn_relu_kernel, dim3((total + 255) / 256), dim3(256), 0, stream,
                           xout, bi[l], ga[l], be[l], mu[l], va[l], total, D - 1);
    };

    hipMemsetAsync(out, 0, (size_t)G * 160 * 4, stream);

    run_layer(x,  nullptr, IN,  4, 64,  0, x1);
    run_layer(x1, nullptr, 256, 4, 64,  1, x2);
    run_layer(x1, x2,      256, 4, 64,  2, x3);
    run_layer(x3, nullptr, 256, 1, 128, 3, x4);

    // ---- GlobalAttention pooling ----
    hipMemsetAsync(gmaxf, 0, (size_t)G * 4, stream);
    hipMemsetAsync(gden,  0, (size_t)G * 4, stream);
    hipLaunchKernelGGL(gate_kernel, dim3(N), dim3(64), 0, stream,
                       x4, pw1, pb1, pw2, pb2, batch, gate, gmaxf);
    hipLaunchKernelGGL(gate_exp_kernel, dim3((N + 255) / 256), dim3(256), 0, stream,
                       gate, gmaxf, batch, gexp, gden, N);
    hipLaunchKernelGGL(pool_agg_kernel, dim3(N), dim3(128), 0, stream,
                       x4, gexp, gden, batch, out);
    hipLaunchKernelGGL(gfeat_kernel, dim3(G), dim3(64), 0, stream, gfeat, gw, gb, out);
}

// Round 2
// 1585.586 us; speedup vs baseline: 2.3680x; 2.3680x over previous
//
#include <hip/hip_runtime.h>
#include <cstdint>
#include <cstddef>

#define NEG_SLOPE 0.2f
#define BN_EPS 1e-5f

// ---------- float <-> order-preserving uint (for atomicMax on float) ----------
__device__ __forceinline__ unsigned int fflip(float f) {
    unsigned int u = __float_as_uint(f);
    return (u & 0x80000000u) ? ~u : (u | 0x80000000u);
}
__device__ __forceinline__ float funflip(unsigned int u) {
    return __uint_as_float((u & 0x80000000u) ? (u & 0x7FFFFFFFu) : ~u);
}

// ---------- fp32 tiled GEMM: C[M,Ncol] = (A (+A2)) @ B, all row-major ----------
#define BM 64
#define BN 64
#define BK 16
__global__ __launch_bounds__(256) void gemm_f32(
    const float* __restrict__ A, const float* __restrict__ A2,
    const float* __restrict__ B, float* __restrict__ C,
    int M, int K, int Ncol) {
    __shared__ float As[BK][BM + 2];
    __shared__ float Bs[BK][BN];
    const int tid = threadIdx.x;
    const int tx = tid & 15;
    const int ty = tid >> 4;
    const int row0 = blockIdx.y * BM;
    const int col0 = blockIdx.x * BN;
    float acc[4][4] = {};

    for (int k0 = 0; k0 < K; k0 += BK) {
        #pragma unroll
        for (int i = 0; i < 4; ++i) {
            int r  = (tid >> 4) + i * 16;
            int kk = tid & 15;
            int grow = row0 + r, gk = k0 + kk;
            float v = 0.f;
            if (grow < M && gk < K) {
                v = A[(size_t)grow * K + gk];
                if (A2) v += A2[(size_t)grow * K + gk];
            }
            As[kk][r] = v;
        }
        #pragma unroll
        for (int i = 0; i < 4; ++i) {
            int kk = (tid >> 6) + i * 4;
            int c  = tid & 63;
            int gk = k0 + kk;
            float v = 0.f;
            if (gk < K) v = B[(size_t)gk * Ncol + col0 + c];
            Bs[kk][c] = v;
        }
        __syncthreads();
        #pragma unroll
        for (int kk = 0; kk < BK; ++kk) {
            float a[4], b[4];
            #pragma unroll
            for (int i = 0; i < 4; ++i) a[i] = As[kk][ty * 4 + i];
            #pragma unroll
            for (int j = 0; j < 4; ++j) b[j] = Bs[kk][tx * 4 + j];
            #pragma unroll
            for (int i = 0; i < 4; ++i)
                #pragma unroll
                for (int j = 0; j < 4; ++j)
                    acc[i][j] = fmaf(a[i], b[j], acc[i][j]);
        }
        __syncthreads();
    }
    #pragma unroll
    for (int i = 0; i < 4; ++i) {
        int r = row0 + ty * 4 + i;
        if (r < M) {
            #pragma unroll
            for (int j = 0; j < 4; ++j)
                C[(size_t)r * Ncol + col0 + tx * 4 + j] = acc[i][j];
        }
    }
}

// ---------- per-node attention logits: alpha_s/d[n,h] = sum_c h[n,h,c]*a[h,c] ----------
__global__ void alpha_kernel(const float* __restrict__ h,
                             const float* __restrict__ avs, const float* __restrict__ avd,
                             float* __restrict__ alpha_s, float* __restrict__ alpha_d,
                             int HEADS, int C) {
    const int n = blockIdx.x;
    const int t = threadIdx.x;
    const int D = HEADS * C;
    __shared__ float ss[256], sd[256];
    float vs = 0.f, vd = 0.f;
    if (t < D) {
        float v = h[(size_t)n * D + t];
        vs = v * avs[t];
        vd = v * avd[t];
    }
    ss[t] = vs; sd[t] = vd;
    __syncthreads();
    // segmented tree-reduce over each head's C contiguous threads
    for (int off = C >> 1; off > 0; off >>= 1) {
        if (t < D && (t & (C - 1)) < off) { ss[t] += ss[t + off]; sd[t] += sd[t + off]; }
        __syncthreads();
    }
    if (t < D && (t & (C - 1)) == 0) {
        int hd = t / C;
        alpha_s[n * HEADS + hd] = ss[t];
        alpha_d[n * HEADS + hd] = sd[t];
    }
}

// ================= CSR build (once per call; shared by all 4 layers) =================
__global__ void deg_count_kernel(const int* __restrict__ ei, int* __restrict__ deg,
                                 int E, int Etot) {
    int e = blockIdx.x * blockDim.x + threadIdx.x;
    if (e >= Etot) return;
    int d = (e < E) ? ei[E + e] : e - E;
    atomicAdd(&deg[d], 1);
}

// single-block exclusive scan of deg[N] -> rowptr[N+1], also fills cursor[N]
__global__ __launch_bounds__(1024) void scan_kernel(const int* __restrict__ deg,
                                                    int* __restrict__ rowptr,
                                                    int* __restrict__ cursor, int N) {
    __shared__ int smem[1024];
    __shared__ int carry;
    if (threadIdx.x == 0) carry = 0;
    __syncthreads();
    for (int base = 0; base < N; base += 1024) {
        int i = base + threadIdx.x;
        int v = (i < N) ? deg[i] : 0;
        smem[threadIdx.x] = v;
        __syncthreads();
        for (int off = 1; off < 1024; off <<= 1) {
            int t = (threadIdx.x >= off) ? smem[threadIdx.x - off] : 0;
            __syncthreads();
            smem[threadIdx.x] += t;
            __syncthreads();
        }
        int excl = smem[threadIdx.x] - v;
        if (i < N) { rowptr[i] = carry + excl; cursor[i] = carry + excl; }
        __syncthreads();
        if (threadIdx.x == 1023) carry += smem[1023];
        __syncthreads();
    }
    if (threadIdx.x == 0) rowptr[N] = carry;
}

__global__ void scatter_kernel(const int* __restrict__ ei, int* __restrict__ cursor,
                               int* __restrict__ csrc, int E, int Etot) {
    int e = blockIdx.x * blockDim.x + threadIdx.x;
    if (e >= Etot) return;
    int s, d;
    if (e < E) { s = ei[e]; d = ei[E + e]; } else { s = d = e - E; }
    int pos = atomicAdd(&cursor[d], 1);
    csrc[pos] = s;
}

// ============ fused GAT edge phase: softmax over incoming edges + weighted agg
// ============ + bias + BN + ReLU.  One block per destination node, no atomics.
template<int HEADS, int C>
__global__ __launch_bounds__(HEADS * C) void gat_agg(
    const int* __restrict__ rowptr, const int* __restrict__ csrc,
    const float* __restrict__ h, const float* __restrict__ asrc,
    const float* __restrict__ adst,
    const float* __restrict__ bias, const float* __restrict__ gamma,
    const float* __restrict__ beta, const float* __restrict__ mean,
    const float* __restrict__ var,
    float* __restrict__ out) {
    constexpr int D = HEADS * C;
    const int d = blockIdx.x;
    const int t = threadIdx.x;
    const int hd = t / C;
    const int c  = t & (C - 1);
    __shared__ float redm[D], reds[D];
    __shared__ float smax[HEADS], sinv[HEADS];
    __shared__ float palpha[HEADS * 64];
    __shared__ int   ssrc[64];

    const int beg = rowptr[d], end = rowptr[d + 1];
    const float ad = adst[d * HEADS + hd];

    // ---- Phase A: per-head online max + exp-sum over this node's edges ----
    float lm = -INFINITY, ls = 0.f;
    for (int j = beg + c; j < end; j += C) {
        int s = csrc[j];
        float v = asrc[s * HEADS + hd] + ad;
        v = v > 0.f ? v : NEG_SLOPE * v;
        float nm = fmaxf(lm, v);
        ls = (ls == 0.f ? 0.f : ls * expf(lm - nm)) + expf(v - nm);
        lm = nm;
    }
    redm[t] = lm; reds[t] = ls;
    __syncthreads();
    for (int off = C >> 1; off > 0; off >>= 1) {
        if (c < off) {
            float m2 = redm[t + off], s2 = reds[t + off];
            float nm = fmaxf(lm, m2);
            ls = (ls == 0.f ? 0.f : ls * expf(lm - nm)) +
                 (s2 == 0.f ? 0.f : s2 * expf(m2 - nm));
            lm = nm;
            redm[t] = lm; reds[t] = ls;
        }
        __syncthreads();
    }
    if (c == 0) { smax[hd] = lm; sinv[hd] = 1.f / (ls + 1e-16f); }
    __syncthreads();

    // ---- Phase B: chunked alpha + weighted aggregation ----
    float acc = 0.f;
    for (int base = beg; base < end; base += 64) {
        int ne = min(64, end - base);
        if (t < ne) ssrc[t] = csrc[base + t];
        __syncthreads();
        {
            int e  = t & 63;
            int hh = t >> 6;
            if (e < ne && hh < HEADS) {
                int s = ssrc[e];
                float v = asrc[s * HEADS + hh] + adst[d * HEADS + hh];
                v = v > 0.f ? v : NEG_SLOPE * v;
                palpha[hh * 64 + e] = expf(v - smax[hh]) * sinv[hh];
            }
        }
        __syncthreads();
        #pragma unroll 4
        for (int e = 0; e < ne; ++e)
            acc = fmaf(h[(size_t)ssrc[e] * D + t], palpha[hd * 64 + e], acc);
        __syncthreads();
    }

    // ---- epilogue: bias + BN(inference) + ReLU ----
    float v = acc + bias[t];
    v = (v - mean[t]) * rsqrtf(var[t] + BN_EPS) * gamma[t] + beta[t];
    out[(size_t)d * D + t] = fmaxf(v, 0.f);
}

// ---------- pooling gate: gate[n] = relu(x4@pw1+pb1)@pw2+pb2; per-graph atomicMax ----------
__global__ void gate_kernel(const float* __restrict__ x4,
                            const float* __restrict__ pw1, const float* __restrict__ pb1,
                            const float* __restrict__ pw2, const float* __restrict__ pb2,
                            const int* __restrict__ batch,
                            float* __restrict__ gate, unsigned int* __restrict__ gmaxf) {
    const int n = blockIdx.x;
    const int lane = threadIdx.x;   // block 64
    float t = 0.f;
    if (lane < 32) {
        float acc = pb1[lane];
        #pragma unroll 4
        for (int c = 0; c < 128; ++c) acc = fmaf(x4[(size_t)n * 128 + c], pw1[c * 32 + lane], acc);
        t = fmaxf(acc, 0.f) * pw2[lane];
    }
    #pragma unroll
    for (int o = 32; o > 0; o >>= 1) t += __shfl_down(t, o, 64);
    if (lane == 0) {
        float gv = t + pb2[0];
        gate[n] = gv;
        atomicMax(&gmaxf[batch[n]], fflip(gv));
    }
}

__global__ void gate_exp_kernel(const float* __restrict__ gate,
                                const unsigned int* __restrict__ gmaxf,
                                const int* __restrict__ batch,
                                float* __restrict__ gexp, float* __restrict__ gden, int N) {
    int n = blockIdx.x * blockDim.x + threadIdx.x;
    if (n >= N) return;
    int b = batch[n];
    float ge = expf(gate[n] - funflip(gmaxf[b]));
    gexp[n] = ge;
    atomicAdd(&gden[b], ge);
}

__global__ void pool_agg_kernel(const float* __restrict__ x4, const float* __restrict__ gexp,
                                const float* __restrict__ gden, const int* __restrict__ batch,
                                float* __restrict__ out) {
    const int n = blockIdx.x;
    const int c = threadIdx.x;      // block 128
    const int b = batch[n];
    float attn = gexp[n] / (gden[b] + 1e-16f);
    atomicAdd(&out[(size_t)b * 160 + c], attn * x4[(size_t)n * 128 + c]);
}

__global__ void gfeat_kernel(const float* __restrict__ gfeat,
                             const float* __restrict__ gw, const float* __restrict__ gb,
                             float* __restrict__ out) {
    const int g = blockIdx.x;
    const int k = threadIdx.x;      // block 64, first 32 active
    if (k < 32) {
        float t = gb[k];
        #pragma unroll
        for (int j = 0; j < 7; ++j) t = fmaf(gfeat[g * 7 + j], gw[j * 32 + k], t);
        out[(size_t)g * 160 + 128 + k] = fmaxf(t, 0.f);
    }
}

// ==========================================================================
extern "C" void kernel_launch(void* const* d_in, const int* in_sizes, int n_in,
                              void* d_out, int out_size, void* d_ws, size_t ws_size,
                              hipStream_t stream) {
    const float* x      = (const float*)d_in[0];
    const int*   ei     = (const int*)  d_in[1];
    const int*   batch  = (const int*)  d_in[2];
    const float* gfeat  = (const float*)d_in[3];

    const int N    = in_sizes[2];
    const int E    = in_sizes[1] / 2;
    const int G    = in_sizes[3] / 7;
    const int IN   = in_sizes[0] / N;
    const int Etot = E + N;

    const float* W[4];  const float* avs[4]; const float* avd[4]; const float* bi[4];
    const float* ga[4]; const float* be[4];  const float* mu[4];  const float* va[4];
    for (int l = 0; l < 4; ++l) {
        int o = 4 + 8 * l;
        W[l]   = (const float*)d_in[o + 0];
        avs[l] = (const float*)d_in[o + 1];
        avd[l] = (const float*)d_in[o + 2];
        bi[l]  = (const float*)d_in[o + 3];
        ga[l]  = (const float*)d_in[o + 4];
        be[l]  = (const float*)d_in[o + 5];
        mu[l]  = (const float*)d_in[o + 6];
        va[l]  = (const float*)d_in[o + 7];
    }
    const float* pw1 = (const float*)d_in[36];
    const float* pb1 = (const float*)d_in[37];
    const float* pw2 = (const float*)d_in[38];
    const float* pb2 = (const float*)d_in[39];
    const float* gw  = (const float*)d_in[40];
    const float* gb  = (const float*)d_in[41];

    float* out = (float*)d_out;

    // ---- workspace carve-up ----
    float* ws = (float*)d_ws;
    float* h    = ws;  ws += (size_t)N * 256;
    float* x1   = ws;  ws += (size_t)N * 256;
    float* x2   = ws;  ws += (size_t)N * 256;
    float* x3   = ws;  ws += (size_t)N * 256;
    float* asrc = ws;  ws += (size_t)N * 4;
    float* adst = ws;  ws += (size_t)N * 4;
    float* gate  = ws; ws += N;
    float* gexp  = ws; ws += N;
    unsigned int* gmaxf = (unsigned int*)ws; ws += G;
    float* gden  = ws; ws += G;
    int* deg    = (int*)ws; ws += N;
    int* cursor = (int*)ws; ws += N;
    int* rowptr = (int*)ws; ws += (N + 1);
    int* csrc   = (int*)ws; ws += Etot;
    float* x4 = x1;    // x1 dead after layer-3 GEMM; reuse for x4 [N,128]

    // ---- CSR build (once; shared by all 4 layers) ----
    hipMemsetAsync(deg, 0, (size_t)N * 4, stream);
    hipLaunchKernelGGL(deg_count_kernel, dim3((Etot + 255) / 256), dim3(256), 0, stream,
                       ei, deg, E, Etot);
    hipLaunchKernelGGL(scan_kernel, dim3(1), dim3(1024), 0, stream, deg, rowptr, cursor, N);
    hipLaunchKernelGGL(scatter_kernel, dim3((Etot + 255) / 256), dim3(256), 0, stream,
                       ei, cursor, csrc, E, Etot);

    auto run_layer = [&](const float* A, const float* A2, int K, int HEADS, int C, int l,
                         float* xout) {
        const int D = HEADS * C;
        dim3 ggrid(D / BN, (N + BM - 1) / BM);
        hipLaunchKernelGGL(gemm_f32, ggrid, dim3(256), 0, stream, A, A2, W[l], h, N, K, D);
        hipLaunchKernelGGL(alpha_kernel, dim3(N), dim3(256), 0, stream,
                           h, avs[l], avd[l], asrc, adst, HEADS, C);
        if (HEADS == 4)
            hipLaunchKernelGGL((gat_agg<4, 64>), dim3(N), dim3(256), 0, stream,
                               rowptr, csrc, h, asrc, adst,
                               bi[l], ga[l], be[l], mu[l], va[l], xout);
        else
            hipLaunchKernelGGL((gat_agg<1, 128>), dim3(N), dim3(128), 0, stream,
                               rowptr, csrc, h, asrc, adst,
                               bi[l], ga[l], be[l], mu[l], va[l], xout);
    };

    hipMemsetAsync(out, 0, (size_t)G * 160 * 4, stream);

    run_layer(x,  nullptr, IN,  4, 64,  0, x1);
    run_layer(x1, nullptr, 256, 4, 64,  1, x2);
    run_layer(x1, x2,      256, 4, 64,  2, x3);
    run_layer(x3, nullptr, 256, 1, 128, 3, x4);

    // ---- GlobalAttention pooling ----
    hipMemsetAsync(gmaxf, 0, (size_t)G * 4, stream);
    hipMemsetAsync(gden,  0, (size_t)G * 4, stream);
    hipLaunchKernelGGL(gate_kernel, dim3(N), dim3(64), 0, stream,
                       x4, pw1, pb1, pw2, pb2, batch, gate, gmaxf);
    hipLaunchKernelGGL(gate_exp_kernel, dim3((N + 255) / 256), dim3(256), 0, stream,
                       gate, gmaxf, batch, gexp, gden, N);
    hipLaunchKernelGGL(pool_agg_kernel, dim3(N), dim3(128), 0, stream,
                       x4, gexp, gden, batch, out);
    hipLaunchKernelGGL(gfeat_kernel, dim3(G), dim3(64), 0, stream, gfeat, gw, gb, out);
}

// Round 3
// 1384.709 us; speedup vs baseline: 2.7115x; 1.1451x over previous
//
#include <hip/hip_runtime.h>
#include <cstdint>
#include <cstddef>

#define NEG_SLOPE 0.2f
#define BN_EPS 1e-5f

typedef __bf16 bf16x8 __attribute__((ext_vector_type(8)));
typedef float  f32x4  __attribute__((ext_vector_type(4)));

// ================= bf16 MFMA GEMM: C_bf16[M,Ncol] = (A (+A2)) @ B =================
// 64x64 tile, 4 waves (2x2 of 32x32), BK=32, mfma_f32_16x16x32_bf16.
// A,B fp32 in global; converted to bf16 during LDS staging. Output stored bf16.
template<bool HAS_A2>
__global__ __launch_bounds__(256) void gemm_bf16_mfma(
    const float* __restrict__ A, const float* __restrict__ A2,
    const float* __restrict__ B, __bf16* __restrict__ C,
    int M, int K, int Ncol) {
    __shared__ __bf16 As[64][40];   // [m][k], pad 32->40 (+16B) to spread banks
    __shared__ __bf16 Bs[64][40];   // [n][k] (transposed: k contiguous for B-frag)
    const int tid  = threadIdx.x;
    const int lane = tid & 63;
    const int w    = tid >> 6;           // wave 0..3
    const int row0 = blockIdx.y * 64;
    const int col0 = blockIdx.x * 64;
    const int wr   = (w >> 1) * 32;      // wave's row quadrant
    const int wc   = (w & 1) * 32;       // wave's col quadrant
    f32x4 acc[2][2] = {};

    const int ar = tid >> 2;             // A stage: row 0..63
    const int ak = (tid & 3) * 8;        // A stage: k chunk
    const int bn = lane;                 // B stage: col 0..63
    const int bk = w * 8;                // B stage: k chunk

    const bool rok = (row0 + ar) < M;
    const int l16 = lane & 15, lk = (lane >> 4) * 8;

    for (int k0 = 0; k0 < K; k0 += 32) {
        // ---- stage A (+A2) -> bf16 ----
        bf16x8 av;
        #pragma unroll
        for (int j = 0; j < 8; ++j) {
            int kk = k0 + ak + j;
            float v = 0.f;
            if (rok && kk < K) {
                v = A[(size_t)(row0 + ar) * K + kk];
                if (HAS_A2) v += A2[(size_t)(row0 + ar) * K + kk];
            }
            av[j] = (__bf16)v;
        }
        *(bf16x8*)&As[ar][ak] = av;
        // ---- stage B transposed -> bf16 ----
        bf16x8 bv;
        #pragma unroll
        for (int j = 0; j < 8; ++j) {
            int kk = k0 + bk + j;
            float v = (kk < K) ? B[(size_t)kk * Ncol + col0 + bn] : 0.f;
            bv[j] = (__bf16)v;
        }
        *(bf16x8*)&Bs[bn][bk] = bv;
        __syncthreads();
        // ---- fragments + 4 MFMA ----
        bf16x8 af[2], bfr[2];
        #pragma unroll
        for (int i = 0; i < 2; ++i) af[i]  = *(const bf16x8*)&As[wr + i * 16 + l16][lk];
        #pragma unroll
        for (int j = 0; j < 2; ++j) bfr[j] = *(const bf16x8*)&Bs[wc + j * 16 + l16][lk];
        #pragma unroll
        for (int i = 0; i < 2; ++i)
            #pragma unroll
            for (int j = 0; j < 2; ++j)
                acc[i][j] = __builtin_amdgcn_mfma_f32_16x16x32_bf16(
                    af[i], bfr[j], acc[i][j], 0, 0, 0);
        __syncthreads();
    }
    // ---- store (C/D layout: col=lane&15, row=(lane>>4)*4+q) ----
    const int lr = (lane >> 4) * 4;
    #pragma unroll
    for (int i = 0; i < 2; ++i)
        #pragma unroll
        for (int q = 0; q < 4; ++q) {
            int row = row0 + wr + i * 16 + lr + q;
            if (row < M)
                #pragma unroll
                for (int j = 0; j < 2; ++j)
                    C[(size_t)row * Ncol + col0 + wc + j * 16 + l16] = (__bf16)acc[i][j][q];
        }
}

// ---------- per-node attention logits from bf16 h ----------
__global__ void alpha_kernel(const __bf16* __restrict__ h,
                             const float* __restrict__ avs, const float* __restrict__ avd,
                             float* __restrict__ alpha_s, float* __restrict__ alpha_d,
                             int HEADS, int C) {
    const int n = blockIdx.x;
    const int t = threadIdx.x;
    const int D = HEADS * C;
    __shared__ float ss[256], sd[256];
    float vs = 0.f, vd = 0.f;
    if (t < D) {
        float v = (float)h[(size_t)n * D + t];
        vs = v * avs[t];
        vd = v * avd[t];
    }
    ss[t] = vs; sd[t] = vd;
    __syncthreads();
    for (int off = C >> 1; off > 0; off >>= 1) {
        if (t < D && (t & (C - 1)) < off) { ss[t] += ss[t + off]; sd[t] += sd[t + off]; }
        __syncthreads();
    }
    if (t < D && (t & (C - 1)) == 0) {
        int hd = t / C;
        alpha_s[n * HEADS + hd] = ss[t];
        alpha_d[n * HEADS + hd] = sd[t];
    }
}

// ================= CSR build (once per call) =================
__global__ void deg_count_kernel(const int* __restrict__ ei, int* __restrict__ deg,
                                 int E, int Etot) {
    int e = blockIdx.x * blockDim.x + threadIdx.x;
    if (e >= Etot) return;
    int d = (e < E) ? ei[E + e] : e - E;
    atomicAdd(&deg[d], 1);
}

__global__ __launch_bounds__(1024) void scan_kernel(const int* __restrict__ deg,
                                                    int* __restrict__ rowptr,
                                                    int* __restrict__ cursor, int N) {
    __shared__ int smem[1024];
    __shared__ int carry;
    if (threadIdx.x == 0) carry = 0;
    __syncthreads();
    for (int base = 0; base < N; base += 1024) {
        int i = base + threadIdx.x;
        int v = (i < N) ? deg[i] : 0;
        smem[threadIdx.x] = v;
        __syncthreads();
        for (int off = 1; off < 1024; off <<= 1) {
            int t = (threadIdx.x >= off) ? smem[threadIdx.x - off] : 0;
            __syncthreads();
            smem[threadIdx.x] += t;
            __syncthreads();
        }
        int excl = smem[threadIdx.x] - v;
        if (i < N) { rowptr[i] = carry + excl; cursor[i] = carry + excl; }
        __syncthreads();
        if (threadIdx.x == 1023) carry += smem[1023];
        __syncthreads();
    }
    if (threadIdx.x == 0) rowptr[N] = carry;
}

__global__ void scatter_kernel(const int* __restrict__ ei, int* __restrict__ cursor,
                               int* __restrict__ csrc, int E, int Etot) {
    int e = blockIdx.x * blockDim.x + threadIdx.x;
    if (e >= Etot) return;
    int s, d;
    if (e < E) { s = ei[e]; d = ei[E + e]; } else { s = d = e - E; }
    int pos = atomicAdd(&cursor[d], 1);
    csrc[pos] = s;
}

// ---------- graph boundary offsets from sorted batch ----------
__global__ void gstart_kernel(const int* __restrict__ batch, int* __restrict__ gstart,
                              int N, int G) {
    int n = blockIdx.x * blockDim.x + threadIdx.x;
    if (n >= N) return;
    int b = batch[n];
    if (n == 0) { for (int g = 0; g <= b; ++g) gstart[g] = 0; }
    else {
        int bp = batch[n - 1];
        for (int g = bp + 1; g <= b; ++g) gstart[g] = n;
    }
    if (n == N - 1) { for (int g = b + 1; g <= G; ++g) gstart[g] = N; }
}

// ============ fused GAT edge phase (softmax + agg + bias + BN + ReLU), no atomics.
// GATE=true additionally computes the pooling gate MLP from the fresh x4 row.
template<int HEADS, int C, bool GATE>
__global__ __launch_bounds__(HEADS * C) void gat_agg(
    const int* __restrict__ rowptr, const int* __restrict__ csrc,
    const __bf16* __restrict__ h, const float* __restrict__ asrc,
    const float* __restrict__ adst,
    const float* __restrict__ bias, const float* __restrict__ gamma,
    const float* __restrict__ beta, const float* __restrict__ mean,
    const float* __restrict__ var,
    float* __restrict__ out,
    const float* __restrict__ pw1, const float* __restrict__ pb1,
    const float* __restrict__ pw2, const float* __restrict__ pb2,
    float* __restrict__ gateout) {
    constexpr int D = HEADS * C;
    const int d = blockIdx.x;
    const int t = threadIdx.x;
    const int hd = t / C;
    const int c  = t & (C - 1);
    __shared__ float redm[D], reds[D];
    __shared__ float smax[HEADS], sinv[HEADS];
    __shared__ float palpha[HEADS * 64];
    __shared__ int   ssrc[64];

    const int beg = rowptr[d], end = rowptr[d + 1];
    const float ad = adst[d * HEADS + hd];

    // ---- Phase A: per-head online max + exp-sum ----
    float lm = -INFINITY, ls = 0.f;
    for (int j = beg + c; j < end; j += C) {
        int s = csrc[j];
        float v = asrc[s * HEADS + hd] + ad;
        v = v > 0.f ? v : NEG_SLOPE * v;
        float nm = fmaxf(lm, v);
        ls = (ls == 0.f ? 0.f : ls * expf(lm - nm)) + expf(v - nm);
        lm = nm;
    }
    redm[t] = lm; reds[t] = ls;
    __syncthreads();
    for (int off = C >> 1; off > 0; off >>= 1) {
        if (c < off) {
            float m2 = redm[t + off], s2 = reds[t + off];
            float nm = fmaxf(lm, m2);
            ls = (ls == 0.f ? 0.f : ls * expf(lm - nm)) +
                 (s2 == 0.f ? 0.f : s2 * expf(m2 - nm));
            lm = nm;
            redm[t] = lm; reds[t] = ls;
        }
        __syncthreads();
    }
    if (c == 0) { smax[hd] = lm; sinv[hd] = 1.f / (ls + 1e-16f); }
    __syncthreads();

    // ---- Phase B: chunked alpha + weighted aggregation (bf16 gather) ----
    float acc = 0.f;
    for (int base = beg; base < end; base += 64) {
        int ne = min(64, end - base);
        if (t < ne) ssrc[t] = csrc[base + t];
        __syncthreads();
        {
            int e  = t & 63;
            int hh = t >> 6;
            if (e < ne && hh < HEADS) {
                int s = ssrc[e];
                float v = asrc[s * HEADS + hh] + adst[d * HEADS + hh];
                v = v > 0.f ? v : NEG_SLOPE * v;
                palpha[hh * 64 + e] = expf(v - smax[hh]) * sinv[hh];
            }
        }
        __syncthreads();
        #pragma unroll 4
        for (int e = 0; e < ne; ++e)
            acc = fmaf((float)h[(size_t)ssrc[e] * D + t], palpha[hd * 64 + e], acc);
        __syncthreads();
    }

    // ---- epilogue: bias + BN(inference) + ReLU ----
    float v = acc + bias[t];
    v = (v - mean[t]) * rsqrtf(var[t] + BN_EPS) * gamma[t] + beta[t];
    v = fmaxf(v, 0.f);
    out[(size_t)d * D + t] = v;

    if constexpr (GATE) {
        // gate[d] = relu(v . pw1 + pb1) . pw2 + pb2   (D==128 threads here)
        redm[t] = v;
        __syncthreads();
        const int j = t & 31, q = t >> 5;
        float p = 0.f;
        #pragma unroll 8
        for (int cc = q * 32; cc < q * 32 + 32; ++cc)
            p = fmaf(redm[cc], pw1[cc * 32 + j], p);
        reds[t] = p;
        __syncthreads();
        if (t < 32) {
            float hid = reds[t] + reds[t + 32] + reds[t + 64] + reds[t + 96] + pb1[t];
            float g = fmaxf(hid, 0.f) * pw2[t];
            #pragma unroll
            for (int o = 16; o > 0; o >>= 1) g += __shfl_xor(g, o, 64);
            if (t == 0) gateout[d] = g + pb2[0];
        }
    }
}

// ---------- block-per-graph pooling: softmax over nodes + weighted sum ----------
__global__ __launch_bounds__(128) void pool_kernel(
    const float* __restrict__ x4, const float* __restrict__ gate,
    const int* __restrict__ gstart, float* __restrict__ out) {
    const int g = blockIdx.x;
    const int t = threadIdx.x;
    const int beg = gstart[g], end = gstart[g + 1];
    __shared__ float red[128];
    __shared__ float wbuf[128];
    // max
    float m = -INFINITY;
    for (int n = beg + t; n < end; n += 128) m = fmaxf(m, gate[n]);
    red[t] = m; __syncthreads();
    for (int off = 64; off > 0; off >>= 1) {
        if (t < off) red[t] = fmaxf(red[t], red[t + off]);
        __syncthreads();
    }
    m = red[0]; __syncthreads();
    // sum of exp
    float s = 0.f;
    for (int n = beg + t; n < end; n += 128) s += expf(gate[n] - m);
    red[t] = s; __syncthreads();
    for (int off = 64; off > 0; off >>= 1) {
        if (t < off) red[t] += red[t + off];
        __syncthreads();
    }
    const float inv = 1.f / (red[0] + 1e-16f);
    __syncthreads();
    // weighted aggregation
    float acc = 0.f;
    for (int base = beg; base < end; base += 128) {
        int ne = min(128, end - base);
        if (t < ne) wbuf[t] = expf(gate[base + t] - m) * inv;
        __syncthreads();
        for (int i = 0; i < ne; ++i)
            acc = fmaf(wbuf[i], x4[(size_t)(base + i) * 128 + t], acc);
        __syncthreads();
    }
    out[(size_t)g * 160 + t] = acc;
}

// ---------- global-feature MLP into d_out[:, 128:160] ----------
__global__ void gfeat_kernel(const float* __restrict__ gfeat,
                             const float* __restrict__ gw, const float* __restrict__ gb,
                             float* __restrict__ out) {
    const int g = blockIdx.x;
    const int k = threadIdx.x;
    if (k < 32) {
        float t = gb[k];
        #pragma unroll
        for (int j = 0; j < 7; ++j) t = fmaf(gfeat[g * 7 + j], gw[j * 32 + k], t);
        out[(size_t)g * 160 + 128 + k] = fmaxf(t, 0.f);
    }
}

// ==========================================================================
extern "C" void kernel_launch(void* const* d_in, const int* in_sizes, int n_in,
                              void* d_out, int out_size, void* d_ws, size_t ws_size,
                              hipStream_t stream) {
    const float* x      = (const float*)d_in[0];
    const int*   ei     = (const int*)  d_in[1];
    const int*   batch  = (const int*)  d_in[2];
    const float* gfeat  = (const float*)d_in[3];

    const int N    = in_sizes[2];
    const int E    = in_sizes[1] / 2;
    const int G    = in_sizes[3] / 7;
    const int IN   = in_sizes[0] / N;
    const int Etot = E + N;

    const float* W[4];  const float* avs[4]; const float* avd[4]; const float* bi[4];
    const float* ga[4]; const float* be[4];  const float* mu[4];  const float* va[4];
    for (int l = 0; l < 4; ++l) {
        int o = 4 + 8 * l;
        W[l]   = (const float*)d_in[o + 0];
        avs[l] = (const float*)d_in[o + 1];
        avd[l] = (const float*)d_in[o + 2];
        bi[l]  = (const float*)d_in[o + 3];
        ga[l]  = (const float*)d_in[o + 4];
        be[l]  = (const float*)d_in[o + 5];
        mu[l]  = (const float*)d_in[o + 6];
        va[l]  = (const float*)d_in[o + 7];
    }
    const float* pw1 = (const float*)d_in[36];
    const float* pb1 = (const float*)d_in[37];
    const float* pw2 = (const float*)d_in[38];
    const float* pb2 = (const float*)d_in[39];
    const float* gw  = (const float*)d_in[40];
    const float* gb  = (const float*)d_in[41];

    float* out = (float*)d_out;

    // ---- workspace carve-up (float units) ----
    float* ws = (float*)d_ws;
    __bf16* h = (__bf16*)ws; ws += (size_t)N * 128;   // N*256 bf16
    float* x1   = ws;  ws += (size_t)N * 256;
    float* x2   = ws;  ws += (size_t)N * 256;
    float* x3   = ws;  ws += (size_t)N * 256;
    float* asrc = ws;  ws += (size_t)N * 4;
    float* adst = ws;  ws += (size_t)N * 4;
    float* gate = ws;  ws += N;
    int* deg    = (int*)ws; ws += N;
    int* cursor = (int*)ws; ws += N;
    int* rowptr = (int*)ws; ws += (N + 1);
    int* csrc   = (int*)ws; ws += Etot;
    int* gstart = (int*)ws; ws += (G + 1);
    float* x4 = x1;    // x1 dead after layer-3 GEMM; reuse for x4 [N,128]

    // ---- CSR build + graph boundaries (shared by all layers) ----
    hipMemsetAsync(deg, 0, (size_t)N * 4, stream);
    hipLaunchKernelGGL(deg_count_kernel, dim3((Etot + 255) / 256), dim3(256), 0, stream,
                       ei, deg, E, Etot);
    hipLaunchKernelGGL(scan_kernel, dim3(1), dim3(1024), 0, stream, deg, rowptr, cursor, N);
    hipLaunchKernelGGL(scatter_kernel, dim3((Etot + 255) / 256), dim3(256), 0, stream,
                       ei, cursor, csrc, E, Etot);
    hipLaunchKernelGGL(gstart_kernel, dim3((N + 255) / 256), dim3(256), 0, stream,
                       batch, gstart, N, G);

    auto run_layer = [&](const float* A, const float* A2, int K, int HEADS, int C, int l,
                         float* xout, bool isGate) {
        const int D = HEADS * C;
        dim3 ggrid(D / 64, (N + 63) / 64);
        if (A2)
            hipLaunchKernelGGL((gemm_bf16_mfma<true>), ggrid, dim3(256), 0, stream,
                               A, A2, W[l], h, N, K, D);
        else
            hipLaunchKernelGGL((gemm_bf16_mfma<false>), ggrid, dim3(256), 0, stream,
                               A, nullptr, W[l], h, N, K, D);
        hipLaunchKernelGGL(alpha_kernel, dim3(N), dim3(256), 0, stream,
                           h, avs[l], avd[l], asrc, adst, HEADS, C);
        if (HEADS == 4)
            hipLaunchKernelGGL((gat_agg<4, 64, false>), dim3(N), dim3(256), 0, stream,
                               rowptr, csrc, h, asrc, adst,
                               bi[l], ga[l], be[l], mu[l], va[l], xout,
                               nullptr, nullptr, nullptr, nullptr, nullptr);
        else
            hipLaunchKernelGGL((gat_agg<1, 128, true>), dim3(N), dim3(128), 0, stream,
                               rowptr, csrc, h, asrc, adst,
                               bi[l], ga[l], be[l], mu[l], va[l], xout,
                               pw1, pb1, pw2, pb2, gate);
    };

    run_layer(x,  nullptr, IN,  4, 64,  0, x1, false);
    run_layer(x1, nullptr, 256, 4, 64,  1, x2, false);
    run_layer(x1, x2,      256, 4, 64,  2, x3, false);
    run_layer(x3, nullptr, 256, 1, 128, 3, x4, true);

    // ---- pooling (block per graph, no atomics) + global-feature MLP ----
    hipLaunchKernelGGL(pool_kernel, dim3(G), dim3(128), 0, stream, x4, gate, gstart, out);
    hipLaunchKernelGGL(gfeat_kernel, dim3(G), dim3(64), 0, stream, gfeat, gw, gb, out);
}

// Round 4
// 922.080 us; speedup vs baseline: 4.0719x; 1.5017x over previous
//
#include <hip/hip_runtime.h>
#include <cstdint>
#include <cstddef>

#define NEG_SLOPE 0.2f
#define BN_EPS 1e-5f

typedef __bf16 bf16x8 __attribute__((ext_vector_type(8)));
typedef float  f32x4  __attribute__((ext_vector_type(4)));

// ---------- prep: x fp32 [N][K] -> bf16 [N][Kpad] zero-padded ----------
__global__ void conv_pad_kernel(const float* __restrict__ x, __bf16* __restrict__ xb,
                                int N, int K, int Kpad) {
    int i = blockIdx.x * blockDim.x + threadIdx.x;
    int total = N * Kpad;
    for (; i < total; i += gridDim.x * blockDim.x) {
        int n = i / Kpad, k = i - n * Kpad;
        xb[i] = (k < K) ? (__bf16)x[(size_t)n * K + k] : (__bf16)0.f;
    }
}

// ---------- prep: W fp32 [K][D] -> WT bf16 [D][Kpad] (transposed, zero-padded) ----------
__global__ void wtrans_kernel(const float* __restrict__ W, __bf16* __restrict__ WT,
                              int K, int D, int Kpad) {
    int col = blockIdx.x;
    for (int k = threadIdx.x; k < Kpad; k += blockDim.x)
        WT[(size_t)col * Kpad + k] = (k < K) ? (__bf16)W[(size_t)k * D + col] : (__bf16)0.f;
}

// ================= LDS-free MFMA GEMM strip + fused alpha =================
// Block: 256 threads (4 waves). DCOLS=256: 64 rows x 256 cols, wave w = head w
// owns col-tile w*64. DCOLS=128: 128 rows x 128 cols, wave -> (rowgroup, coltile).
// A (and A2) bf16 [M][K]; WT bf16 [DCOLS][K]. Writes H bf16 and alpha_s/d.
template<int DCOLS, int HEADS, bool HAS_A2>
__global__ __launch_bounds__(256) void gemm_fused(
    const __bf16* __restrict__ A, const __bf16* __restrict__ A2,
    const __bf16* __restrict__ WT,
    const float* __restrict__ asv, const float* __restrict__ adv,
    __bf16* __restrict__ H, float* __restrict__ alpha_s, float* __restrict__ alpha_d,
    int M, int K) {
    constexpr int RB = (DCOLS == 256) ? 64 : 128;
    const int w    = threadIdx.x >> 6;
    const int lane = threadIdx.x & 63;
    const int l16  = lane & 15, hi4 = lane >> 4;
    const int rg    = (DCOLS == 256) ? 0 : (w >> 1);
    const int ct    = (DCOLS == 256) ? w : (w & 1);
    const int col0w = ct * 64;
    const int rbase = rg * 64;
    const int n0 = blockIdx.x * RB;
    const int lk = hi4 * 8;

    f32x4 acc[4][4] = {};
    int arow[4];
    #pragma unroll
    for (int i = 0; i < 4; ++i) {
        int r = n0 + rbase + i * 16 + l16;
        arow[i] = (r < M) ? r : (M - 1);
    }

    for (int k0 = 0; k0 < K; k0 += 32) {
        bf16x8 af[4], bfr[4];
        #pragma unroll
        for (int i = 0; i < 4; ++i) {
            bf16x8 v = *(const bf16x8*)&A[(size_t)arow[i] * K + k0 + lk];
            if (HAS_A2) {
                bf16x8 v2 = *(const bf16x8*)&A2[(size_t)arow[i] * K + k0 + lk];
                #pragma unroll
                for (int j = 0; j < 8; ++j) v[j] = (__bf16)((float)v[j] + (float)v2[j]);
            }
            af[i] = v;
        }
        #pragma unroll
        for (int j = 0; j < 4; ++j)
            bfr[j] = *(const bf16x8*)&WT[(size_t)(col0w + j * 16 + l16) * K + k0 + lk];
        #pragma unroll
        for (int i = 0; i < 4; ++i)
            #pragma unroll
            for (int j = 0; j < 4; ++j)
                acc[i][j] = __builtin_amdgcn_mfma_f32_16x16x32_bf16(
                    af[i], bfr[j], acc[i][j], 0, 0, 0);
    }

    // ---- epilogue: store H (bf16) ----
    #pragma unroll
    for (int i = 0; i < 4; ++i)
        #pragma unroll
        for (int q = 0; q < 4; ++q) {
            int row = n0 + rbase + i * 16 + hi4 * 4 + q;
            if (row < M)
                #pragma unroll
                for (int j = 0; j < 4; ++j)
                    H[(size_t)row * DCOLS + col0w + j * 16 + l16] = (__bf16)acc[i][j][q];
        }

    // ---- fused alpha: per-row dot with a_src / a_dst over this wave's 64 cols ----
    float asc[4], adc[4];
    #pragma unroll
    for (int j = 0; j < 4; ++j) {
        int c = col0w + j * 16 + l16;
        asc[j] = asv[c]; adc[j] = adv[c];
    }
    __shared__ float as_l[128][2], ad_l[128][2];
    #pragma unroll
    for (int i = 0; i < 4; ++i)
        #pragma unroll
        for (int q = 0; q < 4; ++q) {
            float ps = 0.f, pd = 0.f;
            #pragma unroll
            for (int j = 0; j < 4; ++j) {
                float v = acc[i][j][q];
                ps = fmaf(v, asc[j], ps);
                pd = fmaf(v, adc[j], pd);
            }
            #pragma unroll
            for (int o = 1; o < 16; o <<= 1) {
                ps += __shfl_xor(ps, o, 64);
                pd += __shfl_xor(pd, o, 64);
            }
            int rl = rbase + i * 16 + hi4 * 4 + q;       // row within block
            if constexpr (DCOLS == 256) {
                int row = n0 + rl;
                if (l16 == 0 && row < M) {
                    alpha_s[row * HEADS + w] = ps;
                    alpha_d[row * HEADS + w] = pd;
                }
            } else {
                if (l16 == 0) { as_l[rl][ct] = ps; ad_l[rl][ct] = pd; }
            }
        }
    if constexpr (DCOLS == 128) {
        __syncthreads();
        int t = threadIdx.x;
        if (t < 128) {
            int row = n0 + t;
            if (row < M) {
                alpha_s[row] = as_l[t][0] + as_l[t][1];
                alpha_d[row] = ad_l[t][0] + ad_l[t][1];
            }
        }
    }
}

// ================= CSR build (once per call) =================
__global__ void deg_count_kernel(const int* __restrict__ ei, int* __restrict__ deg,
                                 int E, int Etot) {
    int e = blockIdx.x * blockDim.x + threadIdx.x;
    if (e >= Etot) return;
    int d = (e < E) ? ei[E + e] : e - E;
    atomicAdd(&deg[d], 1);
}

__global__ __launch_bounds__(1024) void scan_kernel(const int* __restrict__ deg,
                                                    int* __restrict__ rowptr,
                                                    int* __restrict__ cursor, int N) {
    __shared__ int smem[1024];
    __shared__ int carry;
    if (threadIdx.x == 0) carry = 0;
    __syncthreads();
    for (int base = 0; base < N; base += 1024) {
        int i = base + threadIdx.x;
        int v = (i < N) ? deg[i] : 0;
        smem[threadIdx.x] = v;
        __syncthreads();
        for (int off = 1; off < 1024; off <<= 1) {
            int t = (threadIdx.x >= off) ? smem[threadIdx.x - off] : 0;
            __syncthreads();
            smem[threadIdx.x] += t;
            __syncthreads();
        }
        int excl = smem[threadIdx.x] - v;
        if (i < N) { rowptr[i] = carry + excl; cursor[i] = carry + excl; }
        __syncthreads();
        if (threadIdx.x == 1023) carry += smem[1023];
        __syncthreads();
    }
    if (threadIdx.x == 0) rowptr[N] = carry;
}

__global__ void scatter_kernel(const int* __restrict__ ei, int* __restrict__ cursor,
                               int* __restrict__ csrc, int E, int Etot) {
    int e = blockIdx.x * blockDim.x + threadIdx.x;
    if (e >= Etot) return;
    int s, d;
    if (e < E) { s = ei[e]; d = ei[E + e]; } else { s = d = e - E; }
    int pos = atomicAdd(&cursor[d], 1);
    csrc[pos] = s;
}

// ---------- graph boundary offsets from sorted batch ----------
__global__ void gstart_kernel(const int* __restrict__ batch, int* __restrict__ gstart,
                              int N, int G) {
    int n = blockIdx.x * blockDim.x + threadIdx.x;
    if (n >= N) return;
    int b = batch[n];
    if (n == 0) { for (int g = 0; g <= b; ++g) gstart[g] = 0; }
    else {
        int bp = batch[n - 1];
        for (int g = bp + 1; g <= b; ++g) gstart[g] = n;
    }
    if (n == N - 1) { for (int g = b + 1; g <= G; ++g) gstart[g] = N; }
}

// ============ fused GAT edge phase (softmax + agg + bias + BN + ReLU), no atomics.
// Output bf16. GATE=true additionally computes the pooling gate MLP.
template<int HEADS, int C, bool GATE>
__global__ __launch_bounds__(HEADS * C) void gat_agg(
    const int* __restrict__ rowptr, const int* __restrict__ csrc,
    const __bf16* __restrict__ h, const float* __restrict__ asrc,
    const float* __restrict__ adst,
    const float* __restrict__ bias, const float* __restrict__ gamma,
    const float* __restrict__ beta, const float* __restrict__ mean,
    const float* __restrict__ var,
    __bf16* __restrict__ out,
    const float* __restrict__ pw1, const float* __restrict__ pb1,
    const float* __restrict__ pw2, const float* __restrict__ pb2,
    float* __restrict__ gateout) {
    constexpr int D = HEADS * C;
    const int d = blockIdx.x;
    const int t = threadIdx.x;
    const int hd = t / C;
    const int c  = t & (C - 1);
    __shared__ float redm[D], reds[D];
    __shared__ float smax[HEADS], sinv[HEADS];
    __shared__ float palpha[HEADS * 64];
    __shared__ int   ssrc[64];

    const int beg = rowptr[d], end = rowptr[d + 1];
    const float ad = adst[d * HEADS + hd];

    // ---- Phase A: per-head online max + exp-sum ----
    float lm = -INFINITY, ls = 0.f;
    for (int j = beg + c; j < end; j += C) {
        int s = csrc[j];
        float v = asrc[s * HEADS + hd] + ad;
        v = v > 0.f ? v : NEG_SLOPE * v;
        float nm = fmaxf(lm, v);
        ls = (ls == 0.f ? 0.f : ls * expf(lm - nm)) + expf(v - nm);
        lm = nm;
    }
    redm[t] = lm; reds[t] = ls;
    __syncthreads();
    for (int off = C >> 1; off > 0; off >>= 1) {
        if (c < off) {
            float m2 = redm[t + off], s2 = reds[t + off];
            float nm = fmaxf(lm, m2);
            ls = (ls == 0.f ? 0.f : ls * expf(lm - nm)) +
                 (s2 == 0.f ? 0.f : s2 * expf(m2 - nm));
            lm = nm;
            redm[t] = lm; reds[t] = ls;
        }
        __syncthreads();
    }
    if (c == 0) { smax[hd] = lm; sinv[hd] = 1.f / (ls + 1e-16f); }
    __syncthreads();

    // ---- Phase B: chunked alpha + weighted aggregation (bf16 gather) ----
    float acc = 0.f;
    for (int base = beg; base < end; base += 64) {
        int ne = min(64, end - base);
        if (t < ne) ssrc[t] = csrc[base + t];
        __syncthreads();
        {
            int e  = t & 63;
            int hh = t >> 6;
            if (e < ne && hh < HEADS) {
                int s = ssrc[e];
                float v = asrc[s * HEADS + hh] + adst[d * HEADS + hh];
                v = v > 0.f ? v : NEG_SLOPE * v;
                palpha[hh * 64 + e] = expf(v - smax[hh]) * sinv[hh];
            }
        }
        __syncthreads();
        #pragma unroll 4
        for (int e = 0; e < ne; ++e)
            acc = fmaf((float)h[(size_t)ssrc[e] * D + t], palpha[hd * 64 + e], acc);
        __syncthreads();
    }

    // ---- epilogue: bias + BN(inference) + ReLU -> bf16 ----
    float v = acc + bias[t];
    v = (v - mean[t]) * rsqrtf(var[t] + BN_EPS) * gamma[t] + beta[t];
    v = fmaxf(v, 0.f);
    out[(size_t)d * D + t] = (__bf16)v;

    if constexpr (GATE) {
        redm[t] = v;
        __syncthreads();
        const int j = t & 31, q = t >> 5;
        float p = 0.f;
        #pragma unroll 8
        for (int cc = q * 32; cc < q * 32 + 32; ++cc)
            p = fmaf(redm[cc], pw1[cc * 32 + j], p);
        reds[t] = p;
        __syncthreads();
        if (t < 32) {
            float hid = reds[t] + reds[t + 32] + reds[t + 64] + reds[t + 96] + pb1[t];
            float g = fmaxf(hid, 0.f) * pw2[t];
            #pragma unroll
            for (int o = 16; o > 0; o >>= 1) g += __shfl_xor(g, o, 64);
            if (t == 0) gateout[d] = g + pb2[0];
        }
    }
}

// ---------- block-per-graph pooling: softmax over nodes + weighted sum ----------
__global__ __launch_bounds__(128) void pool_kernel(
    const __bf16* __restrict__ x4, const float* __restrict__ gate,
    const int* __restrict__ gstart, float* __restrict__ out) {
    const int g = blockIdx.x;
    const int t = threadIdx.x;
    const int beg = gstart[g], end = gstart[g + 1];
    __shared__ float red[128];
    __shared__ float wbuf[128];
    float m = -INFINITY;
    for (int n = beg + t; n < end; n += 128) m = fmaxf(m, gate[n]);
    red[t] = m; __syncthreads();
    for (int off = 64; off > 0; off >>= 1) {
        if (t < off) red[t] = fmaxf(red[t], red[t + off]);
        __syncthreads();
    }
    m = red[0]; __syncthreads();
    float s = 0.f;
    for (int n = beg + t; n < end; n += 128) s += expf(gate[n] - m);
    red[t] = s; __syncthreads();
    for (int off = 64; off > 0; off >>= 1) {
        if (t < off) red[t] += red[t + off];
        __syncthreads();
    }
    const float inv = 1.f / (red[0] + 1e-16f);
    __syncthreads();
    float acc = 0.f;
    for (int base = beg; base < end; base += 128) {
        int ne = min(128, end - base);
        if (t < ne) wbuf[t] = expf(gate[base + t] - m) * inv;
        __syncthreads();
        for (int i = 0; i < ne; ++i)
            acc = fmaf(wbuf[i], (float)x4[(size_t)(base + i) * 128 + t], acc);
        __syncthreads();
    }
    out[(size_t)g * 160 + t] = acc;
}

// ---------- global-feature MLP into d_out[:, 128:160] ----------
__global__ void gfeat_kernel(const float* __restrict__ gfeat,
                             const float* __restrict__ gw, const float* __restrict__ gb,
                             float* __restrict__ out) {
    const int g = blockIdx.x;
    const int k = threadIdx.x;
    if (k < 32) {
        float t = gb[k];
        #pragma unroll
        for (int j = 0; j < 7; ++j) t = fmaf(gfeat[g * 7 + j], gw[j * 32 + k], t);
        out[(size_t)g * 160 + 128 + k] = fmaxf(t, 0.f);
    }
}

// ==========================================================================
extern "C" void kernel_launch(void* const* d_in, const int* in_sizes, int n_in,
                              void* d_out, int out_size, void* d_ws, size_t ws_size,
                              hipStream_t stream) {
    const float* x      = (const float*)d_in[0];
    const int*   ei     = (const int*)  d_in[1];
    const int*   batch  = (const int*)  d_in[2];
    const float* gfeat  = (const float*)d_in[3];

    const int N    = in_sizes[2];
    const int E    = in_sizes[1] / 2;
    const int G    = in_sizes[3] / 7;
    const int IN   = in_sizes[0] / N;
    const int Etot = E + N;
    const int INp  = 64;   // padded K for layer 0

    const float* W[4];  const float* avs[4]; const float* avd[4]; const float* bi[4];
    const float* ga[4]; const float* be[4];  const float* mu[4];  const float* va[4];
    for (int l = 0; l < 4; ++l) {
        int o = 4 + 8 * l;
        W[l]   = (const float*)d_in[o + 0];
        avs[l] = (const float*)d_in[o + 1];
        avd[l] = (const float*)d_in[o + 2];
        bi[l]  = (const float*)d_in[o + 3];
        ga[l]  = (const float*)d_in[o + 4];
        be[l]  = (const float*)d_in[o + 5];
        mu[l]  = (const float*)d_in[o + 6];
        va[l]  = (const float*)d_in[o + 7];
    }
    const float* pw1 = (const float*)d_in[36];
    const float* pb1 = (const float*)d_in[37];
    const float* pw2 = (const float*)d_in[38];
    const float* pb2 = (const float*)d_in[39];
    const float* gw  = (const float*)d_in[40];
    const float* gb  = (const float*)d_in[41];

    float* out = (float*)d_out;

    // ---- workspace carve-up (float units) ----
    float* ws = (float*)d_ws;
    __bf16* xb = (__bf16*)ws; ws += (size_t)N * 32;        // N x 64 bf16
    __bf16* h  = (__bf16*)ws; ws += (size_t)N * 128;       // N x 256 bf16
    __bf16* x1 = (__bf16*)ws; ws += (size_t)N * 128;
    __bf16* x2 = (__bf16*)ws; ws += (size_t)N * 128;
    __bf16* x3 = (__bf16*)ws; ws += (size_t)N * 128;
    __bf16* wt1 = (__bf16*)ws; ws += 256 * 64 / 2;         // [256][64]
    __bf16* wt2 = (__bf16*)ws; ws += 256 * 256 / 2;        // [256][256]
    __bf16* wt3 = (__bf16*)ws; ws += 256 * 256 / 2;
    __bf16* wt4 = (__bf16*)ws; ws += 128 * 256 / 2;        // [128][256]
    float* asrc = ws;  ws += (size_t)N * 4;
    float* adst = ws;  ws += (size_t)N * 4;
    float* gate = ws;  ws += N;
    int* deg    = (int*)ws; ws += N;
    int* cursor = (int*)ws; ws += N;
    int* rowptr = (int*)ws; ws += (N + 1);
    int* csrc   = (int*)ws; ws += Etot;
    int* gstart = (int*)ws; ws += (G + 1);
    __bf16* x4 = x1;   // x1 dead after layer-3 GEMM; reuse for x4 [N][128]

    // ---- prep: convert/pad x, transpose-convert weights ----
    hipLaunchKernelGGL(conv_pad_kernel, dim3(512), dim3(256), 0, stream, x, xb, N, IN, INp);
    hipLaunchKernelGGL(wtrans_kernel, dim3(256), dim3(256), 0, stream, W[0], wt1, IN,  256, 64);
    hipLaunchKernelGGL(wtrans_kernel, dim3(256), dim3(256), 0, stream, W[1], wt2, 256, 256, 256);
    hipLaunchKernelGGL(wtrans_kernel, dim3(256), dim3(256), 0, stream, W[2], wt3, 256, 256, 256);
    hipLaunchKernelGGL(wtrans_kernel, dim3(128), dim3(256), 0, stream, W[3], wt4, 256, 128, 256);

    // ---- CSR build + graph boundaries ----
    hipMemsetAsync(deg, 0, (size_t)N * 4, stream);
    hipLaunchKernelGGL(deg_count_kernel, dim3((Etot + 255) / 256), dim3(256), 0, stream,
                       ei, deg, E, Etot);
    hipLaunchKernelGGL(scan_kernel, dim3(1), dim3(1024), 0, stream, deg, rowptr, cursor, N);
    hipLaunchKernelGGL(scatter_kernel, dim3((Etot + 255) / 256), dim3(256), 0, stream,
                       ei, cursor, csrc, E, Etot);
    hipLaunchKernelGGL(gstart_kernel, dim3((N + 255) / 256), dim3(256), 0, stream,
                       batch, gstart, N, G);

    const int grid256 = (N + 63) / 64;
    const int grid128 = (N + 127) / 128;

    // ---- layer 1: h = xb @ W1; alpha fused ----
    hipLaunchKernelGGL((gemm_fused<256, 4, false>), dim3(grid256), dim3(256), 0, stream,
                       xb, nullptr, wt1, avs[0], avd[0], h, asrc, adst, N, INp);
    hipLaunchKernelGGL((gat_agg<4, 64, false>), dim3(N), dim3(256), 0, stream,
                       rowptr, csrc, h, asrc, adst, bi[0], ga[0], be[0], mu[0], va[0], x1,
                       nullptr, nullptr, nullptr, nullptr, nullptr);
    // ---- layer 2 ----
    hipLaunchKernelGGL((gemm_fused<256, 4, false>), dim3(grid256), dim3(256), 0, stream,
                       x1, nullptr, wt2, avs[1], avd[1], h, asrc, adst, N, 256);
    hipLaunchKernelGGL((gat_agg<4, 64, false>), dim3(N), dim3(256), 0, stream,
                       rowptr, csrc, h, asrc, adst, bi[1], ga[1], be[1], mu[1], va[1], x2,
                       nullptr, nullptr, nullptr, nullptr, nullptr);
    // ---- layer 3 (residual x1+x2) ----
    hipLaunchKernelGGL((gemm_fused<256, 4, true>), dim3(grid256), dim3(256), 0, stream,
                       x1, x2, wt3, avs[2], avd[2], h, asrc, adst, N, 256);
    hipLaunchKernelGGL((gat_agg<4, 64, false>), dim3(N), dim3(256), 0, stream,
                       rowptr, csrc, h, asrc, adst, bi[2], ga[2], be[2], mu[2], va[2], x3,
                       nullptr, nullptr, nullptr, nullptr, nullptr);
    // ---- layer 4 (D=128, 1 head) + fused gate ----
    hipLaunchKernelGGL((gemm_fused<128, 1, false>), dim3(grid128), dim3(256), 0, stream,
                       x3, nullptr, wt4, avs[3], avd[3], h, asrc, adst, N, 256);
    hipLaunchKernelGGL((gat_agg<1, 128, true>), dim3(N), dim3(128), 0, stream,
                       rowptr, csrc, h, asrc, adst, bi[3], ga[3], be[3], mu[3], va[3], x4,
                       pw1, pb1, pw2, pb2, gate);

    // ---- pooling + global-feature MLP ----
    hipLaunchKernelGGL(pool_kernel, dim3(G), dim3(128), 0, stream, x4, gate, gstart, out);
    hipLaunchKernelGGL(gfeat_kernel, dim3(G), dim3(64), 0, stream, gfeat, gw, gb, out);
}

// Round 5
// 774.366 us; speedup vs baseline: 4.8486x; 1.1908x over previous
//
#include <hip/hip_runtime.h>
#include <cstdint>
#include <cstddef>

#define NEG_SLOPE 0.2f
#define BN_EPS 1e-5f

typedef __bf16 bf16x8 __attribute__((ext_vector_type(8)));
typedef float  f32x4  __attribute__((ext_vector_type(4)));

// ---------- prep: x fp32 [N][K] -> bf16 [N][Kpad] zero-padded ----------
__global__ void conv_pad_kernel(const float* __restrict__ x, __bf16* __restrict__ xb,
                                int N, int K, int Kpad) {
    int i = blockIdx.x * blockDim.x + threadIdx.x;
    int total = N * Kpad;
    for (; i < total; i += gridDim.x * blockDim.x) {
        int n = i / Kpad, k = i - n * Kpad;
        xb[i] = (k < K) ? (__bf16)x[(size_t)n * K + k] : (__bf16)0.f;
    }
}

// ---------- prep: W fp32 [K][D] -> WT bf16 [D][Kpad] (transposed, zero-padded) ----------
__global__ void wtrans_kernel(const float* __restrict__ W, __bf16* __restrict__ WT,
                              int K, int D, int Kpad) {
    int col = blockIdx.x;
    for (int k = threadIdx.x; k < Kpad; k += blockDim.x)
        WT[(size_t)col * Kpad + k] = (k < K) ? (__bf16)W[(size_t)k * D + col] : (__bf16)0.f;
}

// ================= LDS-free MFMA GEMM strip + fused alpha =================
template<int DCOLS, int HEADS, bool HAS_A2>
__global__ __launch_bounds__(256) void gemm_fused(
    const __bf16* __restrict__ A, const __bf16* __restrict__ A2,
    const __bf16* __restrict__ WT,
    const float* __restrict__ asv, const float* __restrict__ adv,
    __bf16* __restrict__ H, float* __restrict__ alpha_s, float* __restrict__ alpha_d,
    int M, int K) {
    constexpr int RB = (DCOLS == 256) ? 64 : 128;
    const int w    = threadIdx.x >> 6;
    const int lane = threadIdx.x & 63;
    const int l16  = lane & 15, hi4 = lane >> 4;
    const int rg    = (DCOLS == 256) ? 0 : (w >> 1);
    const int ct    = (DCOLS == 256) ? w : (w & 1);
    const int col0w = ct * 64;
    const int rbase = rg * 64;
    const int n0 = blockIdx.x * RB;
    const int lk = hi4 * 8;

    f32x4 acc[4][4] = {};
    int arow[4];
    #pragma unroll
    for (int i = 0; i < 4; ++i) {
        int r = n0 + rbase + i * 16 + l16;
        arow[i] = (r < M) ? r : (M - 1);
    }

    for (int k0 = 0; k0 < K; k0 += 32) {
        bf16x8 af[4], bfr[4];
        #pragma unroll
        for (int i = 0; i < 4; ++i) {
            bf16x8 v = *(const bf16x8*)&A[(size_t)arow[i] * K + k0 + lk];
            if (HAS_A2) {
                bf16x8 v2 = *(const bf16x8*)&A2[(size_t)arow[i] * K + k0 + lk];
                #pragma unroll
                for (int j = 0; j < 8; ++j) v[j] = (__bf16)((float)v[j] + (float)v2[j]);
            }
            af[i] = v;
        }
        #pragma unroll
        for (int j = 0; j < 4; ++j)
            bfr[j] = *(const bf16x8*)&WT[(size_t)(col0w + j * 16 + l16) * K + k0 + lk];
        #pragma unroll
        for (int i = 0; i < 4; ++i)
            #pragma unroll
            for (int j = 0; j < 4; ++j)
                acc[i][j] = __builtin_amdgcn_mfma_f32_16x16x32_bf16(
                    af[i], bfr[j], acc[i][j], 0, 0, 0);
    }

    #pragma unroll
    for (int i = 0; i < 4; ++i)
        #pragma unroll
        for (int q = 0; q < 4; ++q) {
            int row = n0 + rbase + i * 16 + hi4 * 4 + q;
            if (row < M)
                #pragma unroll
                for (int j = 0; j < 4; ++j)
                    H[(size_t)row * DCOLS + col0w + j * 16 + l16] = (__bf16)acc[i][j][q];
        }

    float asc[4], adc[4];
    #pragma unroll
    for (int j = 0; j < 4; ++j) {
        int c = col0w + j * 16 + l16;
        asc[j] = asv[c]; adc[j] = adv[c];
    }
    __shared__ float as_l[128][2], ad_l[128][2];
    #pragma unroll
    for (int i = 0; i < 4; ++i)
        #pragma unroll
        for (int q = 0; q < 4; ++q) {
            float ps = 0.f, pd = 0.f;
            #pragma unroll
            for (int j = 0; j < 4; ++j) {
                float v = acc[i][j][q];
                ps = fmaf(v, asc[j], ps);
                pd = fmaf(v, adc[j], pd);
            }
            #pragma unroll
            for (int o = 1; o < 16; o <<= 1) {
                ps += __shfl_xor(ps, o, 64);
                pd += __shfl_xor(pd, o, 64);
            }
            int rl = rbase + i * 16 + hi4 * 4 + q;
            if constexpr (DCOLS == 256) {
                int row = n0 + rl;
                if (l16 == 0 && row < M) {
                    alpha_s[row * HEADS + w] = ps;
                    alpha_d[row * HEADS + w] = pd;
                }
            } else {
                if (l16 == 0) { as_l[rl][ct] = ps; ad_l[rl][ct] = pd; }
            }
        }
    if constexpr (DCOLS == 128) {
        __syncthreads();
        int t = threadIdx.x;
        if (t < 128) {
            int row = n0 + t;
            if (row < M) {
                alpha_s[row] = as_l[t][0] + as_l[t][1];
                alpha_d[row] = ad_l[t][0] + ad_l[t][1];
            }
        }
    }
}

// ================= CSR build (once per call) =================
__global__ void deg_count_kernel(const int* __restrict__ ei, int* __restrict__ deg,
                                 int E, int Etot) {
    int e = blockIdx.x * blockDim.x + threadIdx.x;
    if (e >= Etot) return;
    int d = (e < E) ? ei[E + e] : e - E;
    atomicAdd(&deg[d], 1);
}

__global__ __launch_bounds__(1024) void scan_kernel(const int* __restrict__ deg,
                                                    int* __restrict__ rowptr,
                                                    int* __restrict__ cursor, int N) {
    __shared__ int smem[1024];
    __shared__ int carry;
    if (threadIdx.x == 0) carry = 0;
    __syncthreads();
    for (int base = 0; base < N; base += 1024) {
        int i = base + threadIdx.x;
        int v = (i < N) ? deg[i] : 0;
        smem[threadIdx.x] = v;
        __syncthreads();
        for (int off = 1; off < 1024; off <<= 1) {
            int t = (threadIdx.x >= off) ? smem[threadIdx.x - off] : 0;
            __syncthreads();
            smem[threadIdx.x] += t;
            __syncthreads();
        }
        int excl = smem[threadIdx.x] - v;
        if (i < N) { rowptr[i] = carry + excl; cursor[i] = carry + excl; }
        __syncthreads();
        if (threadIdx.x == 1023) carry += smem[1023];
        __syncthreads();
    }
    if (threadIdx.x == 0) rowptr[N] = carry;
}

__global__ void scatter_kernel(const int* __restrict__ ei, int* __restrict__ cursor,
                               int* __restrict__ csrc, int E, int Etot) {
    int e = blockIdx.x * blockDim.x + threadIdx.x;
    if (e >= Etot) return;
    int s, d;
    if (e < E) { s = ei[e]; d = ei[E + e]; } else { s = d = e - E; }
    int pos = atomicAdd(&cursor[d], 1);
    csrc[pos] = s;
}

__global__ void gstart_kernel(const int* __restrict__ batch, int* __restrict__ gstart,
                              int N, int G) {
    int n = blockIdx.x * blockDim.x + threadIdx.x;
    if (n >= N) return;
    int b = batch[n];
    if (n == 0) { for (int g = 0; g <= b; ++g) gstart[g] = 0; }
    else {
        int bp = batch[n - 1];
        for (int g = bp + 1; g <= b; ++g) gstart[g] = n;
    }
    if (n == N - 1) { for (int g = b + 1; g <= G; ++g) gstart[g] = N; }
}

// ============ fused GAT edge phase, restructured: two-pass softmax, butterfly
// ============ shuffle reductions, scalar-base gather. No atomics.
template<int HEADS, int C, bool GATE>
__global__ __launch_bounds__(HEADS * C) void gat_agg(
    const int* __restrict__ rowptr, const int* __restrict__ csrc,
    const __bf16* __restrict__ h, const float* __restrict__ asrc,
    const float* __restrict__ adst,
    const float* __restrict__ bias, const float* __restrict__ gamma,
    const float* __restrict__ beta, const float* __restrict__ mean,
    const float* __restrict__ var,
    __bf16* __restrict__ out,
    const float* __restrict__ pw1, const float* __restrict__ pb1,
    const float* __restrict__ pw2, const float* __restrict__ pb2,
    float* __restrict__ gateout) {
    constexpr int D = HEADS * C;
    const int d = blockIdx.x;
    const int t = threadIdx.x;
    const int hd = t / C;          // head owning column t (aggregation role)
    const int le = t & 63;         // edge slot (logit role)
    const int hh = t >> 6;         // head (logit role); may exceed HEADS-1 when C=128

    __shared__ int   ssrc[64];
    __shared__ float palpha[HEADS * 64];
    __shared__ float smaxb[HEADS], sinvb[HEADS];

    const int beg = rowptr[d], end = rowptr[d + 1];
    const int deg = end - beg;

    const __bf16* hcol = h + t;
    const float* pal = &palpha[hd * 64];
    float a0 = 0.f, a1 = 0.f, a2 = 0.f, a3 = 0.f;

    if (deg <= 64) {
        // ---------- fast path: logits fully in registers/shuffles ----------
        if (t < deg) ssrc[t] = csrc[beg + t];
        __syncthreads();
        if (hh < HEADS) {
            float v = -INFINITY;
            if (le < deg) {
                int s = ssrc[le];
                float lv = asrc[s * HEADS + hh] + adst[d * HEADS + hh];
                v = lv > 0.f ? lv : NEG_SLOPE * lv;
            }
            float mx = v;
            #pragma unroll
            for (int o = 1; o < 64; o <<= 1) mx = fmaxf(mx, __shfl_xor(mx, o, 64));
            float p = (le < deg) ? __expf(v - mx) : 0.f;
            float ps = p;
            #pragma unroll
            for (int o = 1; o < 64; o <<= 1) ps += __shfl_xor(ps, o, 64);
            palpha[hh * 64 + le] = p * (1.f / ps);
        }
        __syncthreads();
        // ---------- aggregation: 4-way unrolled scalar-base gather ----------
        int e = 0;
        for (; e + 4 <= deg; e += 4) {
            int s0 = __builtin_amdgcn_readfirstlane(ssrc[e + 0]);
            int s1 = __builtin_amdgcn_readfirstlane(ssrc[e + 1]);
            int s2 = __builtin_amdgcn_readfirstlane(ssrc[e + 2]);
            int s3 = __builtin_amdgcn_readfirstlane(ssrc[e + 3]);
            float p0 = pal[e + 0], p1 = pal[e + 1], p2 = pal[e + 2], p3 = pal[e + 3];
            a0 = fmaf((float)hcol[(size_t)s0 * D], p0, a0);
            a1 = fmaf((float)hcol[(size_t)s1 * D], p1, a1);
            a2 = fmaf((float)hcol[(size_t)s2 * D], p2, a2);
            a3 = fmaf((float)hcol[(size_t)s3 * D], p3, a3);
        }
        for (; e < deg; ++e) {
            int s0 = __builtin_amdgcn_readfirstlane(ssrc[e]);
            a0 = fmaf((float)hcol[(size_t)s0 * D], pal[e], a0);
        }
    } else {
        // ---------- general path (deg > 64; rare) ----------
        if (hh < HEADS) {
            const float ad = adst[d * HEADS + hh];
            float v = -INFINITY;
            for (int j = beg + le; j < end; j += 64) {
                float lv = asrc[csrc[j] * HEADS + hh] + ad;
                lv = lv > 0.f ? lv : NEG_SLOPE * lv;
                v = fmaxf(v, lv);
            }
            float mx = v;
            #pragma unroll
            for (int o = 1; o < 64; o <<= 1) mx = fmaxf(mx, __shfl_xor(mx, o, 64));
            float ps = 0.f;
            for (int j = beg + le; j < end; j += 64) {
                float lv = asrc[csrc[j] * HEADS + hh] + ad;
                lv = lv > 0.f ? lv : NEG_SLOPE * lv;
                ps += __expf(lv - mx);
            }
            #pragma unroll
            for (int o = 1; o < 64; o <<= 1) ps += __shfl_xor(ps, o, 64);
            if (le == 0) { smaxb[hh] = mx; sinvb[hh] = 1.f / ps; }
        }
        __syncthreads();
        for (int base = beg; base < end; base += 64) {
            int ne = min(64, end - base);
            if (t < ne) ssrc[t] = csrc[base + t];
            __syncthreads();
            if (hh < HEADS && le < ne) {
                int s = ssrc[le];
                float lv = asrc[s * HEADS + hh] + adst[d * HEADS + hh];
                lv = lv > 0.f ? lv : NEG_SLOPE * lv;
                palpha[hh * 64 + le] = __expf(lv - smaxb[hh]) * sinvb[hh];
            }
            __syncthreads();
            for (int e = 0; e < ne; ++e) {
                int s0 = __builtin_amdgcn_readfirstlane(ssrc[e]);
                a0 = fmaf((float)hcol[(size_t)s0 * D], pal[e], a0);
            }
            __syncthreads();
        }
    }

    // ---- epilogue: bias + BN(inference) + ReLU -> bf16 ----
    float acc = (a0 + a1) + (a2 + a3);
    float v = acc + bias[t];
    v = (v - mean[t]) * rsqrtf(var[t] + BN_EPS) * gamma[t] + beta[t];
    v = fmaxf(v, 0.f);
    out[(size_t)d * D + t] = (__bf16)v;

    if constexpr (GATE) {
        __shared__ float redm[D], reds[D];
        redm[t] = v;
        __syncthreads();
        const int j = t & 31, q = t >> 5;
        float p = 0.f;
        #pragma unroll 8
        for (int cc = q * 32; cc < q * 32 + 32; ++cc)
            p = fmaf(redm[cc], pw1[cc * 32 + j], p);
        reds[t] = p;
        __syncthreads();
        if (t < 32) {
            float hid = reds[t] + reds[t + 32] + reds[t + 64] + reds[t + 96] + pb1[t];
            float g = fmaxf(hid, 0.f) * pw2[t];
            #pragma unroll
            for (int o = 16; o > 0; o >>= 1) g += __shfl_xor(g, o, 64);
            if (t == 0) gateout[d] = g + pb2[0];
        }
    }
}

// ---------- block-per-graph pooling ----------
__global__ __launch_bounds__(128) void pool_kernel(
    const __bf16* __restrict__ x4, const float* __restrict__ gate,
    const int* __restrict__ gstart, float* __restrict__ out) {
    const int g = blockIdx.x;
    const int t = threadIdx.x;
    const int beg = gstart[g], end = gstart[g + 1];
    __shared__ float red[128];
    __shared__ float wbuf[128];
    float m = -INFINITY;
    for (int n = beg + t; n < end; n += 128) m = fmaxf(m, gate[n]);
    red[t] = m; __syncthreads();
    for (int off = 64; off > 0; off >>= 1) {
        if (t < off) red[t] = fmaxf(red[t], red[t + off]);
        __syncthreads();
    }
    m = red[0]; __syncthreads();
    float s = 0.f;
    for (int n = beg + t; n < end; n += 128) s += expf(gate[n] - m);
    red[t] = s; __syncthreads();
    for (int off = 64; off > 0; off >>= 1) {
        if (t < off) red[t] += red[t + off];
        __syncthreads();
    }
    const float inv = 1.f / (red[0] + 1e-16f);
    __syncthreads();
    float acc = 0.f;
    for (int base = beg; base < end; base += 128) {
        int ne = min(128, end - base);
        if (t < ne) wbuf[t] = expf(gate[base + t] - m) * inv;
        __syncthreads();
        for (int i = 0; i < ne; ++i)
            acc = fmaf(wbuf[i], (float)x4[(size_t)(base + i) * 128 + t], acc);
        __syncthreads();
    }
    out[(size_t)g * 160 + t] = acc;
}

// ---------- global-feature MLP into d_out[:, 128:160] ----------
__global__ void gfeat_kernel(const float* __restrict__ gfeat,
                             const float* __restrict__ gw, const float* __restrict__ gb,
                             float* __restrict__ out) {
    const int g = blockIdx.x;
    const int k = threadIdx.x;
    if (k < 32) {
        float t = gb[k];
        #pragma unroll
        for (int j = 0; j < 7; ++j) t = fmaf(gfeat[g * 7 + j], gw[j * 32 + k], t);
        out[(size_t)g * 160 + 128 + k] = fmaxf(t, 0.f);
    }
}

// ==========================================================================
extern "C" void kernel_launch(void* const* d_in, const int* in_sizes, int n_in,
                              void* d_out, int out_size, void* d_ws, size_t ws_size,
                              hipStream_t stream) {
    const float* x      = (const float*)d_in[0];
    const int*   ei     = (const int*)  d_in[1];
    const int*   batch  = (const int*)  d_in[2];
    const float* gfeat  = (const float*)d_in[3];

    const int N    = in_sizes[2];
    const int E    = in_sizes[1] / 2;
    const int G    = in_sizes[3] / 7;
    const int IN   = in_sizes[0] / N;
    const int Etot = E + N;
    const int INp  = 64;

    const float* W[4];  const float* avs[4]; const float* avd[4]; const float* bi[4];
    const float* ga[4]; const float* be[4];  const float* mu[4];  const float* va[4];
    for (int l = 0; l < 4; ++l) {
        int o = 4 + 8 * l;
        W[l]   = (const float*)d_in[o + 0];
        avs[l] = (const float*)d_in[o + 1];
        avd[l] = (const float*)d_in[o + 2];
        bi[l]  = (const float*)d_in[o + 3];
        ga[l]  = (const float*)d_in[o + 4];
        be[l]  = (const float*)d_in[o + 5];
        mu[l]  = (const float*)d_in[o + 6];
        va[l]  = (const float*)d_in[o + 7];
    }
    const float* pw1 = (const float*)d_in[36];
    const float* pb1 = (const float*)d_in[37];
    const float* pw2 = (const float*)d_in[38];
    const float* pb2 = (const float*)d_in[39];
    const float* gw  = (const float*)d_in[40];
    const float* gb  = (const float*)d_in[41];

    float* out = (float*)d_out;

    float* ws = (float*)d_ws;
    __bf16* xb = (__bf16*)ws; ws += (size_t)N * 32;
    __bf16* h  = (__bf16*)ws; ws += (size_t)N * 128;
    __bf16* x1 = (__bf16*)ws; ws += (size_t)N * 128;
    __bf16* x2 = (__bf16*)ws; ws += (size_t)N * 128;
    __bf16* x3 = (__bf16*)ws; ws += (size_t)N * 128;
    __bf16* wt1 = (__bf16*)ws; ws += 256 * 64 / 2;
    __bf16* wt2 = (__bf16*)ws; ws += 256 * 256 / 2;
    __bf16* wt3 = (__bf16*)ws; ws += 256 * 256 / 2;
    __bf16* wt4 = (__bf16*)ws; ws += 128 * 256 / 2;
    float* asrc = ws;  ws += (size_t)N * 4;
    float* adst = ws;  ws += (size_t)N * 4;
    float* gate = ws;  ws += N;
    int* deg    = (int*)ws; ws += N;
    int* cursor = (int*)ws; ws += N;
    int* rowptr = (int*)ws; ws += (N + 1);
    int* csrc   = (int*)ws; ws += Etot;
    int* gstart = (int*)ws; ws += (G + 1);
    __bf16* x4 = x1;

    hipLaunchKernelGGL(conv_pad_kernel, dim3(512), dim3(256), 0, stream, x, xb, N, IN, INp);
    hipLaunchKernelGGL(wtrans_kernel, dim3(256), dim3(256), 0, stream, W[0], wt1, IN,  256, 64);
    hipLaunchKernelGGL(wtrans_kernel, dim3(256), dim3(256), 0, stream, W[1], wt2, 256, 256, 256);
    hipLaunchKernelGGL(wtrans_kernel, dim3(256), dim3(256), 0, stream, W[2], wt3, 256, 256, 256);
    hipLaunchKernelGGL(wtrans_kernel, dim3(128), dim3(256), 0, stream, W[3], wt4, 256, 128, 256);

    hipMemsetAsync(deg, 0, (size_t)N * 4, stream);
    hipLaunchKernelGGL(deg_count_kernel, dim3((Etot + 255) / 256), dim3(256), 0, stream,
                       ei, deg, E, Etot);
    hipLaunchKernelGGL(scan_kernel, dim3(1), dim3(1024), 0, stream, deg, rowptr, cursor, N);
    hipLaunchKernelGGL(scatter_kernel, dim3((Etot + 255) / 256), dim3(256), 0, stream,
                       ei, cursor, csrc, E, Etot);
    hipLaunchKernelGGL(gstart_kernel, dim3((N + 255) / 256), dim3(256), 0, stream,
                       batch, gstart, N, G);

    const int grid256 = (N + 63) / 64;
    const int grid128 = (N + 127) / 128;

    hipLaunchKernelGGL((gemm_fused<256, 4, false>), dim3(grid256), dim3(256), 0, stream,
                       xb, nullptr, wt1, avs[0], avd[0], h, asrc, adst, N, INp);
    hipLaunchKernelGGL((gat_agg<4, 64, false>), dim3(N), dim3(256), 0, stream,
                       rowptr, csrc, h, asrc, adst, bi[0], ga[0], be[0], mu[0], va[0], x1,
                       nullptr, nullptr, nullptr, nullptr, nullptr);
    hipLaunchKernelGGL((gemm_fused<256, 4, false>), dim3(grid256), dim3(256), 0, stream,
                       x1, nullptr, wt2, avs[1], avd[1], h, asrc, adst, N, 256);
    hipLaunchKernelGGL((gat_agg<4, 64, false>), dim3(N), dim3(256), 0, stream,
                       rowptr, csrc, h, asrc, adst, bi[1], ga[1], be[1], mu[1], va[1], x2,
                       nullptr, nullptr, nullptr, nullptr, nullptr);
    hipLaunchKernelGGL((gemm_fused<256, 4, true>), dim3(grid256), dim3(256), 0, stream,
                       x1, x2, wt3, avs[2], avd[2], h, asrc, adst, N, 256);
    hipLaunchKernelGGL((gat_agg<4, 64, false>), dim3(N), dim3(256), 0, stream,
                       rowptr, csrc, h, asrc, adst, bi[2], ga[2], be[2], mu[2], va[2], x3,
                       nullptr, nullptr, nullptr, nullptr, nullptr);
    hipLaunchKernelGGL((gemm_fused<128, 1, false>), dim3(grid128), dim3(256), 0, stream,
                       x3, nullptr, wt4, avs[3], avd[3], h, asrc, adst, N, 256);
    hipLaunchKernelGGL((gat_agg<1, 128, true>), dim3(N), dim3(128), 0, stream,
                       rowptr, csrc, h, asrc, adst, bi[3], ga[3], be[3], mu[3], va[3], x4,
                       pw1, pb1, pw2, pb2, gate);

    hipLaunchKernelGGL(pool_kernel, dim3(G), dim3(128), 0, stream, x4, gate, gstart, out);
    hipLaunchKernelGGL(gfeat_kernel, dim3(G), dim3(64), 0, stream, gfeat, gw, gb, out);
}

// Round 6
// 676.824 us; speedup vs baseline: 5.5474x; 1.1441x over previous
//
#include <hip/hip_runtime.h>
#include <cstdint>
#include <cstddef>

#define NEG_SLOPE 0.2f
#define BN_EPS 1e-5f

typedef __bf16 bf16x8 __attribute__((ext_vector_type(8)));
typedef __bf16 bf16x4 __attribute__((ext_vector_type(4)));
typedef __bf16 bf16x2 __attribute__((ext_vector_type(2)));
typedef float  f32x4  __attribute__((ext_vector_type(4)));

// ---------- prep: x fp32 [N][K] -> bf16 [N][Kpad] zero-padded ----------
__global__ void conv_pad_kernel(const float* __restrict__ x, __bf16* __restrict__ xb,
                                int N, int K, int Kpad) {
    int i = blockIdx.x * blockDim.x + threadIdx.x;
    int total = N * Kpad;
    for (; i < total; i += gridDim.x * blockDim.x) {
        int n = i / Kpad, k = i - n * Kpad;
        xb[i] = (k < K) ? (__bf16)x[(size_t)n * K + k] : (__bf16)0.f;
    }
}

// ---------- prep: W fp32 [K][D] -> WT bf16 [D][Kpad] ----------
__global__ void wtrans_kernel(const float* __restrict__ W, __bf16* __restrict__ WT,
                              int K, int D, int Kpad) {
    int col = blockIdx.x;
    for (int k = threadIdx.x; k < Kpad; k += blockDim.x)
        WT[(size_t)col * Kpad + k] = (k < K) ? (__bf16)W[(size_t)k * D + col] : (__bf16)0.f;
}

// ================= LDS-free MFMA GEMM strip + fused alpha =================
template<int DCOLS, int HEADS, bool HAS_A2>
__global__ __launch_bounds__(256) void gemm_fused(
    const __bf16* __restrict__ A, const __bf16* __restrict__ A2,
    const __bf16* __restrict__ WT,
    const float* __restrict__ asv, const float* __restrict__ adv,
    __bf16* __restrict__ H, float* __restrict__ alpha_s, float* __restrict__ alpha_d,
    int M, int K) {
    constexpr int RB = (DCOLS == 256) ? 64 : 128;
    const int w    = threadIdx.x >> 6;
    const int lane = threadIdx.x & 63;
    const int l16  = lane & 15, hi4 = lane >> 4;
    const int rg    = (DCOLS == 256) ? 0 : (w >> 1);
    const int ct    = (DCOLS == 256) ? w : (w & 1);
    const int col0w = ct * 64;
    const int rbase = rg * 64;
    const int n0 = blockIdx.x * RB;
    const int lk = hi4 * 8;

    f32x4 acc[4][4] = {};
    int arow[4];
    #pragma unroll
    for (int i = 0; i < 4; ++i) {
        int r = n0 + rbase + i * 16 + l16;
        arow[i] = (r < M) ? r : (M - 1);
    }

    for (int k0 = 0; k0 < K; k0 += 32) {
        bf16x8 af[4], bfr[4];
        #pragma unroll
        for (int i = 0; i < 4; ++i) {
            bf16x8 v = *(const bf16x8*)&A[(size_t)arow[i] * K + k0 + lk];
            if (HAS_A2) {
                bf16x8 v2 = *(const bf16x8*)&A2[(size_t)arow[i] * K + k0 + lk];
                #pragma unroll
                for (int j = 0; j < 8; ++j) v[j] = (__bf16)((float)v[j] + (float)v2[j]);
            }
            af[i] = v;
        }
        #pragma unroll
        for (int j = 0; j < 4; ++j)
            bfr[j] = *(const bf16x8*)&WT[(size_t)(col0w + j * 16 + l16) * K + k0 + lk];
        #pragma unroll
        for (int i = 0; i < 4; ++i)
            #pragma unroll
            for (int j = 0; j < 4; ++j)
                acc[i][j] = __builtin_amdgcn_mfma_f32_16x16x32_bf16(
                    af[i], bfr[j], acc[i][j], 0, 0, 0);
    }

    #pragma unroll
    for (int i = 0; i < 4; ++i)
        #pragma unroll
        for (int q = 0; q < 4; ++q) {
            int row = n0 + rbase + i * 16 + hi4 * 4 + q;
            if (row < M)
                #pragma unroll
                for (int j = 0; j < 4; ++j)
                    H[(size_t)row * DCOLS + col0w + j * 16 + l16] = (__bf16)acc[i][j][q];
        }

    float asc[4], adc[4];
    #pragma unroll
    for (int j = 0; j < 4; ++j) {
        int c = col0w + j * 16 + l16;
        asc[j] = asv[c]; adc[j] = adv[c];
    }
    __shared__ float as_l[128][2], ad_l[128][2];
    #pragma unroll
    for (int i = 0; i < 4; ++i)
        #pragma unroll
        for (int q = 0; q < 4; ++q) {
            float ps = 0.f, pd = 0.f;
            #pragma unroll
            for (int j = 0; j < 4; ++j) {
                float v = acc[i][j][q];
                ps = fmaf(v, asc[j], ps);
                pd = fmaf(v, adc[j], pd);
            }
            #pragma unroll
            for (int o = 1; o < 16; o <<= 1) {
                ps += __shfl_xor(ps, o, 64);
                pd += __shfl_xor(pd, o, 64);
            }
            int rl = rbase + i * 16 + hi4 * 4 + q;
            if constexpr (DCOLS == 256) {
                int row = n0 + rl;
                if (l16 == 0 && row < M) {
                    alpha_s[row * HEADS + w] = ps;
                    alpha_d[row * HEADS + w] = pd;
                }
            } else {
                if (l16 == 0) { as_l[rl][ct] = ps; ad_l[rl][ct] = pd; }
            }
        }
    if constexpr (DCOLS == 128) {
        __syncthreads();
        int t = threadIdx.x;
        if (t < 128) {
            int row = n0 + t;
            if (row < M) {
                alpha_s[row] = as_l[t][0] + as_l[t][1];
                alpha_d[row] = ad_l[t][0] + ad_l[t][1];
            }
        }
    }
}

// ================= CSR build (once per call) =================
__global__ void deg_count_kernel(const int* __restrict__ ei, int* __restrict__ deg,
                                 int E, int Etot) {
    int e = blockIdx.x * blockDim.x + threadIdx.x;
    if (e >= Etot) return;
    int d = (e < E) ? ei[E + e] : e - E;
    atomicAdd(&deg[d], 1);
}

// single-block scan, chunk-serial per thread (few barriers)
__global__ __launch_bounds__(1024) void scan_kernel(const int* __restrict__ deg,
                                                    int* __restrict__ rowptr,
                                                    int* __restrict__ cursor, int N) {
    __shared__ int sums[1024];
    const int t = threadIdx.x;
    const int CH = (N + 1023) / 1024;
    const int b0 = min(t * CH, N);
    const int b1 = min(b0 + CH, N);
    int s = 0;
    for (int i = b0; i < b1; ++i) s += deg[i];
    sums[t] = s;
    __syncthreads();
    for (int off = 1; off < 1024; off <<= 1) {
        int v = (t >= off) ? sums[t - off] : 0;
        __syncthreads();
        sums[t] += v;
        __syncthreads();
    }
    int run = sums[t] - s;   // exclusive prefix of this thread's chunk
    for (int i = b0; i < b1; ++i) {
        rowptr[i] = run; cursor[i] = run; run += deg[i];
    }
    if (t == 1023) rowptr[N] = sums[1023];
}

__global__ void scatter_kernel(const int* __restrict__ ei, int* __restrict__ cursor,
                               int* __restrict__ csrc, int E, int Etot) {
    int e = blockIdx.x * blockDim.x + threadIdx.x;
    if (e >= Etot) return;
    int s, d;
    if (e < E) { s = ei[e]; d = ei[E + e]; } else { s = d = e - E; }
    int pos = atomicAdd(&cursor[d], 1);
    csrc[pos] = s;
}

__global__ void gstart_kernel(const int* __restrict__ batch, int* __restrict__ gstart,
                              int N, int G) {
    int n = blockIdx.x * blockDim.x + threadIdx.x;
    if (n >= N) return;
    int b = batch[n];
    if (n == 0) { for (int g = 0; g <= b; ++g) gstart[g] = 0; }
    else {
        int bp = batch[n - 1];
        for (int g = bp + 1; g <= b; ++g) gstart[g] = n;
    }
    if (n == N - 1) { for (int g = b + 1; g <= G; ++g) gstart[g] = N; }
}

// ============ wave-per-node GAT edge phase: one 64-lane wave owns one dst node.
// Lane owns VPL=D/64 columns (dwordx2/dword gather). No block barriers in the
// main phase; intra-wave LDS ordering via explicit s_waitcnt.
template<int HEADS, int C, bool GATE>
__global__ __launch_bounds__(256) void gat_agg(
    const int* __restrict__ rowptr, const int* __restrict__ csrc,
    const __bf16* __restrict__ hf, const float* __restrict__ asrc,
    const float* __restrict__ adst,
    const float* __restrict__ bias, const float* __restrict__ gamma,
    const float* __restrict__ beta, const float* __restrict__ mean,
    const float* __restrict__ var,
    __bf16* __restrict__ out,
    const float* __restrict__ pw1, const float* __restrict__ pb1,
    const float* __restrict__ pw2, const float* __restrict__ pb2,
    float* __restrict__ gateout, int N) {
    constexpr int D = HEADS * C;
    constexpr int VPL = D / 64;
    using bvec = typename std::conditional<VPL == 4, bf16x4, bf16x2>::type;

    const int wid  = threadIdx.x >> 6;
    const int lane = threadIdx.x & 63;
    const int node = blockIdx.x * 4 + wid;

    __shared__ int   soff[4][64];          // per-wave: src-row byte offsets
    __shared__ float pal[4][64][HEADS];    // per-wave: normalized alpha per head
    __shared__ float x4row[4][128];        // GATE only

    if (node < N) {
        const int beg = rowptr[node], end = rowptr[node + 1];
        const int deg = end - beg;
        const int c0 = lane * VPL;
        const int hd = c0 / C;             // head of my columns
        const char* hb = (const char*)hf + (size_t)c0 * 2;

        float ad[HEADS];
        #pragma unroll
        for (int h = 0; h < HEADS; ++h) ad[h] = adst[node * HEADS + h];  // uniform -> s_load

        float accv[VPL] = {};

        if (deg <= 64) {
            // ---- logits: lane = edge slot ----
            const bool act = lane < deg;
            int msrc = act ? csrc[beg + lane] : 0;
            float lv[HEADS];
            if constexpr (HEADS == 4) {
                float4 a4 = ((const float4*)asrc)[msrc];
                lv[0] = a4.x; lv[1] = a4.y; lv[2] = a4.z; lv[3] = a4.w;
            } else {
                lv[0] = asrc[msrc];
            }
            float p[HEADS];
            #pragma unroll
            for (int h = 0; h < HEADS; ++h) {
                float v;
                if (act) { v = lv[h] + ad[h]; v = v > 0.f ? v : NEG_SLOPE * v; }
                else v = -INFINITY;
                float mx = v;
                #pragma unroll
                for (int o = 1; o < 64; o <<= 1) mx = fmaxf(mx, __shfl_xor(mx, o, 64));
                float pe = act ? __expf(v - mx) : 0.f;
                float ps = pe;
                #pragma unroll
                for (int o = 1; o < 64; o <<= 1) ps += __shfl_xor(ps, o, 64);
                p[h] = pe * (1.f / (ps + 1e-16f));
            }
            soff[wid][lane] = msrc * (D * 2);
            if constexpr (HEADS == 4)
                *(float4*)&pal[wid][lane][0] = make_float4(p[0], p[1], p[2], p[3]);
            else
                pal[wid][lane][0] = p[0];
            asm volatile("s_waitcnt lgkmcnt(0)" ::: "memory");

            // ---- aggregation: one dwordx2 row-slice per edge per lane ----
            int e = 0;
            for (; e + 4 <= deg; e += 4) {
                int o0 = soff[wid][e + 0], o1 = soff[wid][e + 1];
                int o2 = soff[wid][e + 2], o3 = soff[wid][e + 3];
                float q0 = pal[wid][e + 0][hd], q1 = pal[wid][e + 1][hd];
                float q2 = pal[wid][e + 2][hd], q3 = pal[wid][e + 3][hd];
                bvec v0 = *(const bvec*)(hb + o0);
                bvec v1 = *(const bvec*)(hb + o1);
                bvec v2 = *(const bvec*)(hb + o2);
                bvec v3 = *(const bvec*)(hb + o3);
                #pragma unroll
                for (int i = 0; i < VPL; ++i) {
                    accv[i] = fmaf((float)v0[i], q0, accv[i]);
                    accv[i] = fmaf((float)v1[i], q1, accv[i]);
                    accv[i] = fmaf((float)v2[i], q2, accv[i]);
                    accv[i] = fmaf((float)v3[i], q3, accv[i]);
                }
            }
            for (; e < deg; ++e) {
                int o0 = soff[wid][e];
                float q0 = pal[wid][e][hd];
                bvec v0 = *(const bvec*)(hb + o0);
                #pragma unroll
                for (int i = 0; i < VPL; ++i)
                    accv[i] = fmaf((float)v0[i], q0, accv[i]);
            }
        } else {
            // ---- general path (deg > 64; rare): strided two-pass per wave ----
            float mx[HEADS], sm[HEADS], inv[HEADS];
            #pragma unroll
            for (int h = 0; h < HEADS; ++h) mx[h] = -INFINITY;
            for (int j = beg + lane; j < end; j += 64) {
                int s = csrc[j];
                #pragma unroll
                for (int h = 0; h < HEADS; ++h) {
                    float v = asrc[s * HEADS + h] + ad[h];
                    v = v > 0.f ? v : NEG_SLOPE * v;
                    mx[h] = fmaxf(mx[h], v);
                }
            }
            #pragma unroll
            for (int h = 0; h < HEADS; ++h) {
                #pragma unroll
                for (int o = 1; o < 64; o <<= 1) mx[h] = fmaxf(mx[h], __shfl_xor(mx[h], o, 64));
                sm[h] = 0.f;
            }
            for (int j = beg + lane; j < end; j += 64) {
                int s = csrc[j];
                #pragma unroll
                for (int h = 0; h < HEADS; ++h) {
                    float v = asrc[s * HEADS + h] + ad[h];
                    v = v > 0.f ? v : NEG_SLOPE * v;
                    sm[h] += __expf(v - mx[h]);
                }
            }
            #pragma unroll
            for (int h = 0; h < HEADS; ++h) {
                #pragma unroll
                for (int o = 1; o < 64; o <<= 1) sm[h] += __shfl_xor(sm[h], o, 64);
                inv[h] = 1.f / (sm[h] + 1e-16f);
            }
            for (int base = beg; base < end; base += 64) {
                int ne = min(64, end - base);
                bool act = lane < ne;
                int msrc = act ? csrc[base + lane] : 0;
                soff[wid][lane] = msrc * (D * 2);
                #pragma unroll
                for (int h = 0; h < HEADS; ++h) {
                    float pv = 0.f;
                    if (act) {
                        float v = asrc[msrc * HEADS + h] + ad[h];
                        v = v > 0.f ? v : NEG_SLOPE * v;
                        pv = __expf(v - mx[h]) * inv[h];
                    }
                    pal[wid][lane][h] = pv;
                }
                asm volatile("s_waitcnt lgkmcnt(0)" ::: "memory");
                for (int e = 0; e < ne; ++e) {
                    int o0 = soff[wid][e];
                    float q0 = pal[wid][e][hd];
                    bvec v0 = *(const bvec*)(hb + o0);
                    #pragma unroll
                    for (int i = 0; i < VPL; ++i)
                        accv[i] = fmaf((float)v0[i], q0, accv[i]);
                }
                asm volatile("s_waitcnt lgkmcnt(0)" ::: "memory");
            }
        }

        // ---- epilogue: bias + BN(inference) + ReLU -> bf16 ----
        bvec ov;
        #pragma unroll
        for (int i = 0; i < VPL; ++i) {
            int c = c0 + i;
            float v = accv[i] + bias[c];
            v = (v - mean[c]) * rsqrtf(var[c] + BN_EPS) * gamma[c] + beta[c];
            v = fmaxf(v, 0.f);
            ov[i] = (__bf16)v;
            if constexpr (GATE) x4row[wid][c] = v;
        }
        *(bvec*)&out[(size_t)node * D + c0] = ov;
    }

    if constexpr (GATE) {
        __syncthreads();
        const int nib = threadIdx.x >> 6;
        const int gnode = blockIdx.x * 4 + nib;
        const int j = lane & 31;
        if (lane < 32 && gnode < N) {
            float hid = pb1[j];
            #pragma unroll 16
            for (int cc = 0; cc < 128; ++cc)
                hid = fmaf(x4row[nib][cc], pw1[cc * 32 + j], hid);
            float g = fmaxf(hid, 0.f) * pw2[j];
            #pragma unroll
            for (int o = 16; o > 0; o >>= 1) g += __shfl_xor(g, o, 64);
            if (j == 0) gateout[gnode] = g + pb2[0];
        }
    }
}

// ---------- block-per-graph pooling ----------
__global__ __launch_bounds__(128) void pool_kernel(
    const __bf16* __restrict__ x4, const float* __restrict__ gate,
    const int* __restrict__ gstart, float* __restrict__ out) {
    const int g = blockIdx.x;
    const int t = threadIdx.x;
    const int beg = gstart[g], end = gstart[g + 1];
    __shared__ float red[128];
    __shared__ float wbuf[128];
    float m = -INFINITY;
    for (int n = beg + t; n < end; n += 128) m = fmaxf(m, gate[n]);
    red[t] = m; __syncthreads();
    for (int off = 64; off > 0; off >>= 1) {
        if (t < off) red[t] = fmaxf(red[t], red[t + off]);
        __syncthreads();
    }
    m = red[0]; __syncthreads();
    float s = 0.f;
    for (int n = beg + t; n < end; n += 128) s += expf(gate[n] - m);
    red[t] = s; __syncthreads();
    for (int off = 64; off > 0; off >>= 1) {
        if (t < off) red[t] += red[t + off];
        __syncthreads();
    }
    const float inv = 1.f / (red[0] + 1e-16f);
    __syncthreads();
    float acc = 0.f;
    for (int base = beg; base < end; base += 128) {
        int ne = min(128, end - base);
        if (t < ne) wbuf[t] = expf(gate[base + t] - m) * inv;
        __syncthreads();
        for (int i = 0; i < ne; ++i)
            acc = fmaf(wbuf[i], (float)x4[(size_t)(base + i) * 128 + t], acc);
        __syncthreads();
    }
    out[(size_t)g * 160 + t] = acc;
}

// ---------- global-feature MLP into d_out[:, 128:160] ----------
__global__ void gfeat_kernel(const float* __restrict__ gfeat,
                             const float* __restrict__ gw, const float* __restrict__ gb,
                             float* __restrict__ out) {
    const int g = blockIdx.x;
    const int k = threadIdx.x;
    if (k < 32) {
        float t = gb[k];
        #pragma unroll
        for (int j = 0; j < 7; ++j) t = fmaf(gfeat[g * 7 + j], gw[j * 32 + k], t);
        out[(size_t)g * 160 + 128 + k] = fmaxf(t, 0.f);
    }
}

// ==========================================================================
extern "C" void kernel_launch(void* const* d_in, const int* in_sizes, int n_in,
                              void* d_out, int out_size, void* d_ws, size_t ws_size,
                              hipStream_t stream) {
    const float* x      = (const float*)d_in[0];
    const int*   ei     = (const int*)  d_in[1];
    const int*   batch  = (const int*)  d_in[2];
    const float* gfeat  = (const float*)d_in[3];

    const int N    = in_sizes[2];
    const int E    = in_sizes[1] / 2;
    const int G    = in_sizes[3] / 7;
    const int IN   = in_sizes[0] / N;
    const int Etot = E + N;
    const int INp  = 64;

    const float* W[4];  const float* avs[4]; const float* avd[4]; const float* bi[4];
    const float* ga[4]; const float* be[4];  const float* mu[4];  const float* va[4];
    for (int l = 0; l < 4; ++l) {
        int o = 4 + 8 * l;
        W[l]   = (const float*)d_in[o + 0];
        avs[l] = (const float*)d_in[o + 1];
        avd[l] = (const float*)d_in[o + 2];
        bi[l]  = (const float*)d_in[o + 3];
        ga[l]  = (const float*)d_in[o + 4];
        be[l]  = (const float*)d_in[o + 5];
        mu[l]  = (const float*)d_in[o + 6];
        va[l]  = (const float*)d_in[o + 7];
    }
    const float* pw1 = (const float*)d_in[36];
    const float* pb1 = (const float*)d_in[37];
    const float* pw2 = (const float*)d_in[38];
    const float* pb2 = (const float*)d_in[39];
    const float* gw  = (const float*)d_in[40];
    const float* gb  = (const float*)d_in[41];

    float* out = (float*)d_out;

    float* ws = (float*)d_ws;
    __bf16* xb = (__bf16*)ws; ws += (size_t)N * 32;
    __bf16* h  = (__bf16*)ws; ws += (size_t)N * 128;
    __bf16* x1 = (__bf16*)ws; ws += (size_t)N * 128;
    __bf16* x2 = (__bf16*)ws; ws += (size_t)N * 128;
    __bf16* x3 = (__bf16*)ws; ws += (size_t)N * 128;
    __bf16* wt1 = (__bf16*)ws; ws += 256 * 64 / 2;
    __bf16* wt2 = (__bf16*)ws; ws += 256 * 256 / 2;
    __bf16* wt3 = (__bf16*)ws; ws += 256 * 256 / 2;
    __bf16* wt4 = (__bf16*)ws; ws += 128 * 256 / 2;
    float* asrc = ws;  ws += (size_t)N * 4;
    float* adst = ws;  ws += (size_t)N * 4;
    float* gate = ws;  ws += N;
    int* deg    = (int*)ws; ws += N;
    int* cursor = (int*)ws; ws += N;
    int* rowptr = (int*)ws; ws += (N + 1);
    int* csrc   = (int*)ws; ws += Etot;
    int* gstart = (int*)ws; ws += (G + 1);
    __bf16* x4 = x1;

    hipLaunchKernelGGL(conv_pad_kernel, dim3(512), dim3(256), 0, stream, x, xb, N, IN, INp);
    hipLaunchKernelGGL(wtrans_kernel, dim3(256), dim3(256), 0, stream, W[0], wt1, IN,  256, 64);
    hipLaunchKernelGGL(wtrans_kernel, dim3(256), dim3(256), 0, stream, W[1], wt2, 256, 256, 256);
    hipLaunchKernelGGL(wtrans_kernel, dim3(256), dim3(256), 0, stream, W[2], wt3, 256, 256, 256);
    hipLaunchKernelGGL(wtrans_kernel, dim3(128), dim3(256), 0, stream, W[3], wt4, 256, 128, 256);

    hipMemsetAsync(deg, 0, (size_t)N * 4, stream);
    hipLaunchKernelGGL(deg_count_kernel, dim3((Etot + 255) / 256), dim3(256), 0, stream,
                       ei, deg, E, Etot);
    hipLaunchKernelGGL(scan_kernel, dim3(1), dim3(1024), 0, stream, deg, rowptr, cursor, N);
    hipLaunchKernelGGL(scatter_kernel, dim3((Etot + 255) / 256), dim3(256), 0, stream,
                       ei, cursor, csrc, E, Etot);
    hipLaunchKernelGGL(gstart_kernel, dim3((N + 255) / 256), dim3(256), 0, stream,
                       batch, gstart, N, G);

    const int grid256 = (N + 63) / 64;
    const int grid128 = (N + 127) / 128;
    const int gatgrid = (N + 3) / 4;

    hipLaunchKernelGGL((gemm_fused<256, 4, false>), dim3(grid256), dim3(256), 0, stream,
                       xb, nullptr, wt1, avs[0], avd[0], h, asrc, adst, N, INp);
    hipLaunchKernelGGL((gat_agg<4, 64, false>), dim3(gatgrid), dim3(256), 0, stream,
                       rowptr, csrc, h, asrc, adst, bi[0], ga[0], be[0], mu[0], va[0], x1,
                       nullptr, nullptr, nullptr, nullptr, nullptr, N);
    hipLaunchKernelGGL((gemm_fused<256, 4, false>), dim3(grid256), dim3(256), 0, stream,
                       x1, nullptr, wt2, avs[1], avd[1], h, asrc, adst, N, 256);
    hipLaunchKernelGGL((gat_agg<4, 64, false>), dim3(gatgrid), dim3(256), 0, stream,
                       rowptr, csrc, h, asrc, adst, bi[1], ga[1], be[1], mu[1], va[1], x2,
                       nullptr, nullptr, nullptr, nullptr, nullptr, N);
    hipLaunchKernelGGL((gemm_fused<256, 4, true>), dim3(grid256), dim3(256), 0, stream,
                       x1, x2, wt3, avs[2], avd[2], h, asrc, adst, N, 256);
    hipLaunchKernelGGL((gat_agg<4, 64, false>), dim3(gatgrid), dim3(256), 0, stream,
                       rowptr, csrc, h, asrc, adst, bi[2], ga[2], be[2], mu[2], va[2], x3,
                       nullptr, nullptr, nullptr, nullptr, nullptr, N);
    hipLaunchKernelGGL((gemm_fused<128, 1, false>), dim3(grid128), dim3(256), 0, stream,
                       x3, nullptr, wt4, avs[3], avd[3], h, asrc, adst, N, 256);
    hipLaunchKernelGGL((gat_agg<1, 128, true>), dim3(gatgrid), dim3(256), 0, stream,
                       rowptr, csrc, h, asrc, adst, bi[3], ga[3], be[3], mu[3], va[3], x4,
                       pw1, pb1, pw2, pb2, gate, N);

    hipLaunchKernelGGL(pool_kernel, dim3(G), dim3(128), 0, stream, x4, gate, gstart, out);
    hipLaunchKernelGGL(gfeat_kernel, dim3(G), dim3(64), 0, stream, gfeat, gw, gb, out);
}

// Round 7
// 581.742 us; speedup vs baseline: 6.4541x; 1.1634x over previous
//
#include <hip/hip_runtime.h>
#include <cstdint>
#include <cstddef>

#define NEG_SLOPE 0.2f
#define BN_EPS 1e-5f

typedef __bf16 bf16x8 __attribute__((ext_vector_type(8)));
typedef __bf16 bf16x4 __attribute__((ext_vector_type(4)));
typedef __bf16 bf16x2 __attribute__((ext_vector_type(2)));
typedef float  f32x4  __attribute__((ext_vector_type(4)));

// ---------- prep: x fp32 [N][K] -> bf16 [N][Kpad] zero-padded ----------
__global__ void conv_pad_kernel(const float* __restrict__ x, __bf16* __restrict__ xb,
                                int N, int K, int Kpad) {
    int i = blockIdx.x * blockDim.x + threadIdx.x;
    int total = N * Kpad;
    for (; i < total; i += gridDim.x * blockDim.x) {
        int n = i / Kpad, k = i - n * Kpad;
        xb[i] = (k < K) ? (__bf16)x[(size_t)n * K + k] : (__bf16)0.f;
    }
}

// ---------- prep: all 4 weight transposes in one launch ----------
__global__ void wtrans_all_kernel(const float* __restrict__ W1, const float* __restrict__ W2,
                                  const float* __restrict__ W3, const float* __restrict__ W4,
                                  __bf16* __restrict__ wt1, __bf16* __restrict__ wt2,
                                  __bf16* __restrict__ wt3, __bf16* __restrict__ wt4, int IN) {
    int b = blockIdx.x;
    const float* W; __bf16* WT; int K, D, Kpad, col;
    if (b < 256)      { W = W1; WT = wt1; K = IN;  D = 256; Kpad = 64;  col = b; }
    else if (b < 512) { W = W2; WT = wt2; K = 256; D = 256; Kpad = 256; col = b - 256; }
    else if (b < 768) { W = W3; WT = wt3; K = 256; D = 256; Kpad = 256; col = b - 512; }
    else              { W = W4; WT = wt4; K = 256; D = 128; Kpad = 256; col = b - 768; }
    for (int k = threadIdx.x; k < Kpad; k += blockDim.x)
        WT[(size_t)col * Kpad + k] = (k < K) ? (__bf16)W[(size_t)k * D + col] : (__bf16)0.f;
}

// ================= LDS-free MFMA GEMM strip + fused alpha =================
template<int DCOLS, int HEADS, bool HAS_A2>
__global__ __launch_bounds__(256) void gemm_fused(
    const __bf16* __restrict__ A, const __bf16* __restrict__ A2,
    const __bf16* __restrict__ WT,
    const float* __restrict__ asv, const float* __restrict__ adv,
    __bf16* __restrict__ H, float* __restrict__ alpha_s, float* __restrict__ alpha_d,
    int M, int K) {
    constexpr int RB = (DCOLS == 256) ? 64 : 128;
    const int w    = threadIdx.x >> 6;
    const int lane = threadIdx.x & 63;
    const int l16  = lane & 15, hi4 = lane >> 4;
    const int rg    = (DCOLS == 256) ? 0 : (w >> 1);
    const int ct    = (DCOLS == 256) ? w : (w & 1);
    const int col0w = ct * 64;
    const int rbase = rg * 64;
    const int n0 = blockIdx.x * RB;
    const int lk = hi4 * 8;

    f32x4 acc[4][4] = {};
    int arow[4];
    #pragma unroll
    for (int i = 0; i < 4; ++i) {
        int r = n0 + rbase + i * 16 + l16;
        arow[i] = (r < M) ? r : (M - 1);
    }

    for (int k0 = 0; k0 < K; k0 += 32) {
        bf16x8 af[4], bfr[4];
        #pragma unroll
        for (int i = 0; i < 4; ++i) {
            bf16x8 v = *(const bf16x8*)&A[(size_t)arow[i] * K + k0 + lk];
            if (HAS_A2) {
                bf16x8 v2 = *(const bf16x8*)&A2[(size_t)arow[i] * K + k0 + lk];
                #pragma unroll
                for (int j = 0; j < 8; ++j) v[j] = (__bf16)((float)v[j] + (float)v2[j]);
            }
            af[i] = v;
        }
        #pragma unroll
        for (int j = 0; j < 4; ++j)
            bfr[j] = *(const bf16x8*)&WT[(size_t)(col0w + j * 16 + l16) * K + k0 + lk];
        #pragma unroll
        for (int i = 0; i < 4; ++i)
            #pragma unroll
            for (int j = 0; j < 4; ++j)
                acc[i][j] = __builtin_amdgcn_mfma_f32_16x16x32_bf16(
                    af[i], bfr[j], acc[i][j], 0, 0, 0);
    }

    #pragma unroll
    for (int i = 0; i < 4; ++i)
        #pragma unroll
        for (int q = 0; q < 4; ++q) {
            int row = n0 + rbase + i * 16 + hi4 * 4 + q;
            if (row < M)
                #pragma unroll
                for (int j = 0; j < 4; ++j)
                    H[(size_t)row * DCOLS + col0w + j * 16 + l16] = (__bf16)acc[i][j][q];
        }

    float asc[4], adc[4];
    #pragma unroll
    for (int j = 0; j < 4; ++j) {
        int c = col0w + j * 16 + l16;
        asc[j] = asv[c]; adc[j] = adv[c];
    }
    __shared__ float as_l[128][2], ad_l[128][2];
    #pragma unroll
    for (int i = 0; i < 4; ++i)
        #pragma unroll
        for (int q = 0; q < 4; ++q) {
            float ps = 0.f, pd = 0.f;
            #pragma unroll
            for (int j = 0; j < 4; ++j) {
                float v = acc[i][j][q];
                ps = fmaf(v, asc[j], ps);
                pd = fmaf(v, adc[j], pd);
            }
            #pragma unroll
            for (int o = 1; o < 16; o <<= 1) {
                ps += __shfl_xor(ps, o, 64);
                pd += __shfl_xor(pd, o, 64);
            }
            int rl = rbase + i * 16 + hi4 * 4 + q;
            if constexpr (DCOLS == 256) {
                int row = n0 + rl;
                if (l16 == 0 && row < M) {
                    alpha_s[row * HEADS + w] = ps;
                    alpha_d[row * HEADS + w] = pd;
                }
            } else {
                if (l16 == 0) { as_l[rl][ct] = ps; ad_l[rl][ct] = pd; }
            }
        }
    if constexpr (DCOLS == 128) {
        __syncthreads();
        int t = threadIdx.x;
        if (t < 128) {
            int row = n0 + t;
            if (row < M) {
                alpha_s[row] = as_l[t][0] + as_l[t][1];
                alpha_d[row] = ad_l[t][0] + ad_l[t][1];
            }
        }
    }
}

// ================= CSR build (once per call) =================
__global__ void deg_count_kernel(const int* __restrict__ ei, int* __restrict__ deg,
                                 int E, int Etot) {
    int e = blockIdx.x * blockDim.x + threadIdx.x;
    if (e >= Etot) return;
    int d = (e < E) ? ei[E + e] : e - E;
    atomicAdd(&deg[d], 1);
}

// ---------- 3-phase multi-block exclusive scan of deg[N] ----------
#define SCB 4096   // elements per block (256 threads x 16)
__global__ __launch_bounds__(256) void scan1_kernel(const int* __restrict__ deg,
                                                    int* __restrict__ bsum, int N) {
    __shared__ int ts[256];
    const int t = threadIdx.x;
    const int base = blockIdx.x * SCB + t * 16;
    int s = 0;
    #pragma unroll
    for (int i = 0; i < 16; ++i) {
        int idx = base + i;
        if (idx < N) s += deg[idx];
    }
    ts[t] = s;
    __syncthreads();
    for (int off = 128; off > 0; off >>= 1) {
        if (t < off) ts[t] += ts[t + off];
        __syncthreads();
    }
    if (t == 0) bsum[blockIdx.x] = ts[0];
}

__global__ __launch_bounds__(256) void scan2_kernel(const int* __restrict__ bsum,
                                                    int* __restrict__ bpref, int B,
                                                    int* __restrict__ rowptrN) {
    __shared__ int sm[256];
    const int t = threadIdx.x;
    int v = (t < B) ? bsum[t] : 0;
    sm[t] = v;
    __syncthreads();
    for (int off = 1; off < 256; off <<= 1) {
        int u = (t >= off) ? sm[t - off] : 0;
        __syncthreads();
        sm[t] += u;
        __syncthreads();
    }
    if (t < B) bpref[t] = sm[t] - v;
    if (t == 255) *rowptrN = sm[255];
}

__global__ __launch_bounds__(256) void scan3_kernel(const int* __restrict__ deg,
                                                    const int* __restrict__ bpref,
                                                    int* __restrict__ rowptr,
                                                    int* __restrict__ cursor, int N) {
    __shared__ int ts[256];
    const int t = threadIdx.x;
    const int base = blockIdx.x * SCB + t * 16;
    int d[16];
    int s = 0;
    #pragma unroll
    for (int i = 0; i < 16; ++i) {
        int idx = base + i;
        d[i] = (idx < N) ? deg[idx] : 0;
        s += d[i];
    }
    ts[t] = s;
    __syncthreads();
    for (int off = 1; off < 256; off <<= 1) {
        int u = (t >= off) ? ts[t - off] : 0;
        __syncthreads();
        ts[t] += u;
        __syncthreads();
    }
    int run = bpref[blockIdx.x] + ts[t] - s;
    #pragma unroll
    for (int i = 0; i < 16; ++i) {
        int idx = base + i;
        if (idx < N) { rowptr[idx] = run; cursor[idx] = run; run += d[i]; }
    }
}

__global__ void scatter_kernel(const int* __restrict__ ei, int* __restrict__ cursor,
                               int* __restrict__ csrc, int E, int Etot) {
    int e = blockIdx.x * blockDim.x + threadIdx.x;
    if (e >= Etot) return;
    int s, d;
    if (e < E) { s = ei[e]; d = ei[E + e]; } else { s = d = e - E; }
    int pos = atomicAdd(&cursor[d], 1);
    csrc[pos] = s;
}

__global__ void gstart_kernel(const int* __restrict__ batch, int* __restrict__ gstart,
                              int N, int G) {
    int n = blockIdx.x * blockDim.x + threadIdx.x;
    if (n >= N) return;
    int b = batch[n];
    if (n == 0) { for (int g = 0; g <= b; ++g) gstart[g] = 0; }
    else {
        int bp = batch[n - 1];
        for (int g = bp + 1; g <= b; ++g) gstart[g] = n;
    }
    if (n == N - 1) { for (int g = b + 1; g <= G; ++g) gstart[g] = N; }
}

// ============ wave-per-node GAT edge phase ============
template<int HEADS, int C, bool GATE>
__global__ __launch_bounds__(256) void gat_agg(
    const int* __restrict__ rowptr, const int* __restrict__ csrc,
    const __bf16* __restrict__ hf, const float* __restrict__ asrc,
    const float* __restrict__ adst,
    const float* __restrict__ bias, const float* __restrict__ gamma,
    const float* __restrict__ beta, const float* __restrict__ mean,
    const float* __restrict__ var,
    __bf16* __restrict__ out,
    const float* __restrict__ pw1, const float* __restrict__ pb1,
    const float* __restrict__ pw2, const float* __restrict__ pb2,
    float* __restrict__ gateout, int N) {
    constexpr int D = HEADS * C;
    constexpr int VPL = D / 64;
    using bvec = typename std::conditional<VPL == 4, bf16x4, bf16x2>::type;

    const int wid  = threadIdx.x >> 6;
    const int lane = threadIdx.x & 63;
    const int node = blockIdx.x * 4 + wid;

    __shared__ int   soff[4][64];
    __shared__ float pal[4][64][HEADS];
    __shared__ float x4row[4][128];

    if (node < N) {
        const int beg = rowptr[node], end = rowptr[node + 1];
        const int deg = end - beg;
        const int c0 = lane * VPL;
        const int hd = c0 / C;
        const char* hb = (const char*)hf + (size_t)c0 * 2;

        float ad[HEADS];
        #pragma unroll
        for (int h = 0; h < HEADS; ++h) ad[h] = adst[node * HEADS + h];

        float accv[VPL] = {};

        if (deg <= 64) {
            const bool act = lane < deg;
            int msrc = act ? csrc[beg + lane] : 0;
            float lv[HEADS];
            if constexpr (HEADS == 4) {
                float4 a4 = ((const float4*)asrc)[msrc];
                lv[0] = a4.x; lv[1] = a4.y; lv[2] = a4.z; lv[3] = a4.w;
            } else {
                lv[0] = asrc[msrc];
            }
            float p[HEADS];
            #pragma unroll
            for (int h = 0; h < HEADS; ++h) {
                float v;
                if (act) { v = lv[h] + ad[h]; v = v > 0.f ? v : NEG_SLOPE * v; }
                else v = -INFINITY;
                float mx = v;
                #pragma unroll
                for (int o = 1; o < 64; o <<= 1) mx = fmaxf(mx, __shfl_xor(mx, o, 64));
                float pe = act ? __expf(v - mx) : 0.f;
                float ps = pe;
                #pragma unroll
                for (int o = 1; o < 64; o <<= 1) ps += __shfl_xor(ps, o, 64);
                p[h] = pe * (1.f / (ps + 1e-16f));
            }
            soff[wid][lane] = msrc * (D * 2);
            if constexpr (HEADS == 4)
                *(float4*)&pal[wid][lane][0] = make_float4(p[0], p[1], p[2], p[3]);
            else
                pal[wid][lane][0] = p[0];
            asm volatile("s_waitcnt lgkmcnt(0)" ::: "memory");

            int e = 0;
            for (; e + 4 <= deg; e += 4) {
                int o0 = soff[wid][e + 0], o1 = soff[wid][e + 1];
                int o2 = soff[wid][e + 2], o3 = soff[wid][e + 3];
                float q0 = pal[wid][e + 0][hd], q1 = pal[wid][e + 1][hd];
                float q2 = pal[wid][e + 2][hd], q3 = pal[wid][e + 3][hd];
                bvec v0 = *(const bvec*)(hb + o0);
                bvec v1 = *(const bvec*)(hb + o1);
                bvec v2 = *(const bvec*)(hb + o2);
                bvec v3 = *(const bvec*)(hb + o3);
                #pragma unroll
                for (int i = 0; i < VPL; ++i) {
                    accv[i] = fmaf((float)v0[i], q0, accv[i]);
                    accv[i] = fmaf((float)v1[i], q1, accv[i]);
                    accv[i] = fmaf((float)v2[i], q2, accv[i]);
                    accv[i] = fmaf((float)v3[i], q3, accv[i]);
                }
            }
            for (; e < deg; ++e) {
                int o0 = soff[wid][e];
                float q0 = pal[wid][e][hd];
                bvec v0 = *(const bvec*)(hb + o0);
                #pragma unroll
                for (int i = 0; i < VPL; ++i)
                    accv[i] = fmaf((float)v0[i], q0, accv[i]);
            }
        } else {
            float mx[HEADS], sm[HEADS], inv[HEADS];
            #pragma unroll
            for (int h = 0; h < HEADS; ++h) mx[h] = -INFINITY;
            for (int j = beg + lane; j < end; j += 64) {
                int s = csrc[j];
                #pragma unroll
                for (int h = 0; h < HEADS; ++h) {
                    float v = asrc[s * HEADS + h] + ad[h];
                    v = v > 0.f ? v : NEG_SLOPE * v;
                    mx[h] = fmaxf(mx[h], v);
                }
            }
            #pragma unroll
            for (int h = 0; h < HEADS; ++h) {
                #pragma unroll
                for (int o = 1; o < 64; o <<= 1) mx[h] = fmaxf(mx[h], __shfl_xor(mx[h], o, 64));
                sm[h] = 0.f;
            }
            for (int j = beg + lane; j < end; j += 64) {
                int s = csrc[j];
                #pragma unroll
                for (int h = 0; h < HEADS; ++h) {
                    float v = asrc[s * HEADS + h] + ad[h];
                    v = v > 0.f ? v : NEG_SLOPE * v;
                    sm[h] += __expf(v - mx[h]);
                }
            }
            #pragma unroll
            for (int h = 0; h < HEADS; ++h) {
                #pragma unroll
                for (int o = 1; o < 64; o <<= 1) sm[h] += __shfl_xor(sm[h], o, 64);
                inv[h] = 1.f / (sm[h] + 1e-16f);
            }
            for (int base = beg; base < end; base += 64) {
                int ne = min(64, end - base);
                bool act = lane < ne;
                int msrc = act ? csrc[base + lane] : 0;
                soff[wid][lane] = msrc * (D * 2);
                #pragma unroll
                for (int h = 0; h < HEADS; ++h) {
                    float pv = 0.f;
                    if (act) {
                        float v = asrc[msrc * HEADS + h] + ad[h];
                        v = v > 0.f ? v : NEG_SLOPE * v;
                        pv = __expf(v - mx[h]) * inv[h];
                    }
                    pal[wid][lane][h] = pv;
                }
                asm volatile("s_waitcnt lgkmcnt(0)" ::: "memory");
                for (int e = 0; e < ne; ++e) {
                    int o0 = soff[wid][e];
                    float q0 = pal[wid][e][hd];
                    bvec v0 = *(const bvec*)(hb + o0);
                    #pragma unroll
                    for (int i = 0; i < VPL; ++i)
                        accv[i] = fmaf((float)v0[i], q0, accv[i]);
                }
                asm volatile("s_waitcnt lgkmcnt(0)" ::: "memory");
            }
        }

        bvec ov;
        #pragma unroll
        for (int i = 0; i < VPL; ++i) {
            int c = c0 + i;
            float v = accv[i] + bias[c];
            v = (v - mean[c]) * rsqrtf(var[c] + BN_EPS) * gamma[c] + beta[c];
            v = fmaxf(v, 0.f);
            ov[i] = (__bf16)v;
            if constexpr (GATE) x4row[wid][c] = v;
        }
        *(bvec*)&out[(size_t)node * D + c0] = ov;
    }

    if constexpr (GATE) {
        __syncthreads();
        const int nib = threadIdx.x >> 6;
        const int gnode = blockIdx.x * 4 + nib;
        const int j = lane & 31;
        if (lane < 32 && gnode < N) {
            float hid = pb1[j];
            #pragma unroll 16
            for (int cc = 0; cc < 128; ++cc)
                hid = fmaf(x4row[nib][cc], pw1[cc * 32 + j], hid);
            float g = fmaxf(hid, 0.f) * pw2[j];
            #pragma unroll
            for (int o = 16; o > 0; o >>= 1) g += __shfl_xor(g, o, 64);
            if (j == 0) gateout[gnode] = g + pb2[0];
        }
    }
}

// ---------- block-per-graph pooling ----------
__global__ __launch_bounds__(128) void pool_kernel(
    const __bf16* __restrict__ x4, const float* __restrict__ gate,
    const int* __restrict__ gstart, float* __restrict__ out) {
    const int g = blockIdx.x;
    const int t = threadIdx.x;
    const int beg = gstart[g], end = gstart[g + 1];
    __shared__ float red[128];
    __shared__ float wbuf[128];
    float m = -INFINITY;
    for (int n = beg + t; n < end; n += 128) m = fmaxf(m, gate[n]);
    red[t] = m; __syncthreads();
    for (int off = 64; off > 0; off >>= 1) {
        if (t < off) red[t] = fmaxf(red[t], red[t + off]);
        __syncthreads();
    }
    m = red[0]; __syncthreads();
    float s = 0.f;
    for (int n = beg + t; n < end; n += 128) s += expf(gate[n] - m);
    red[t] = s; __syncthreads();
    for (int off = 64; off > 0; off >>= 1) {
        if (t < off) red[t] += red[t + off];
        __syncthreads();
    }
    const float inv = 1.f / (red[0] + 1e-16f);
    __syncthreads();
    float acc = 0.f;
    for (int base = beg; base < end; base += 128) {
        int ne = min(128, end - base);
        if (t < ne) wbuf[t] = expf(gate[base + t] - m) * inv;
        __syncthreads();
        for (int i = 0; i < ne; ++i)
            acc = fmaf(wbuf[i], (float)x4[(size_t)(base + i) * 128 + t], acc);
        __syncthreads();
    }
    out[(size_t)g * 160 + t] = acc;
}

// ---------- global-feature MLP into d_out[:, 128:160] ----------
__global__ void gfeat_kernel(const float* __restrict__ gfeat,
                             const float* __restrict__ gw, const float* __restrict__ gb,
                             float* __restrict__ out) {
    const int g = blockIdx.x;
    const int k = threadIdx.x;
    if (k < 32) {
        float t = gb[k];
        #pragma unroll
        for (int j = 0; j < 7; ++j) t = fmaf(gfeat[g * 7 + j], gw[j * 32 + k], t);
        out[(size_t)g * 160 + 128 + k] = fmaxf(t, 0.f);
    }
}

// ==========================================================================
extern "C" void kernel_launch(void* const* d_in, const int* in_sizes, int n_in,
                              void* d_out, int out_size, void* d_ws, size_t ws_size,
                              hipStream_t stream) {
    const float* x      = (const float*)d_in[0];
    const int*   ei     = (const int*)  d_in[1];
    const int*   batch  = (const int*)  d_in[2];
    const float* gfeat  = (const float*)d_in[3];

    const int N    = in_sizes[2];
    const int E    = in_sizes[1] / 2;
    const int G    = in_sizes[3] / 7;
    const int IN   = in_sizes[0] / N;
    const int Etot = E + N;
    const int INp  = 64;

    const float* W[4];  const float* avs[4]; const float* avd[4]; const float* bi[4];
    const float* ga[4]; const float* be[4];  const float* mu[4];  const float* va[4];
    for (int l = 0; l < 4; ++l) {
        int o = 4 + 8 * l;
        W[l]   = (const float*)d_in[o + 0];
        avs[l] = (const float*)d_in[o + 1];
        avd[l] = (const float*)d_in[o + 2];
        bi[l]  = (const float*)d_in[o + 3];
        ga[l]  = (const float*)d_in[o + 4];
        be[l]  = (const float*)d_in[o + 5];
        mu[l]  = (const float*)d_in[o + 6];
        va[l]  = (const float*)d_in[o + 7];
    }
    const float* pw1 = (const float*)d_in[36];
    const float* pb1 = (const float*)d_in[37];
    const float* pw2 = (const float*)d_in[38];
    const float* pb2 = (const float*)d_in[39];
    const float* gw  = (const float*)d_in[40];
    const float* gb  = (const float*)d_in[41];

    float* out = (float*)d_out;

    float* ws = (float*)d_ws;
    __bf16* xb = (__bf16*)ws; ws += (size_t)N * 32;
    __bf16* h  = (__bf16*)ws; ws += (size_t)N * 128;
    __bf16* x1 = (__bf16*)ws; ws += (size_t)N * 128;
    __bf16* x2 = (__bf16*)ws; ws += (size_t)N * 128;
    __bf16* x3 = (__bf16*)ws; ws += (size_t)N * 128;
    __bf16* wt1 = (__bf16*)ws; ws += 256 * 64 / 2;
    __bf16* wt2 = (__bf16*)ws; ws += 256 * 256 / 2;
    __bf16* wt3 = (__bf16*)ws; ws += 256 * 256 / 2;
    __bf16* wt4 = (__bf16*)ws; ws += 128 * 256 / 2;
    float* asrc = ws;  ws += (size_t)N * 4;
    float* adst = ws;  ws += (size_t)N * 4;
    float* gate = ws;  ws += N;
    int* deg    = (int*)ws; ws += N;
    int* cursor = (int*)ws; ws += N;
    int* rowptr = (int*)ws; ws += (N + 1);
    int* csrc   = (int*)ws; ws += Etot;
    int* gstart = (int*)ws; ws += (G + 1);
    int* bsum   = (int*)ws; ws += 256;
    int* bpref  = (int*)ws; ws += 256;
    __bf16* x4 = x1;

    const int SB = (N + SCB - 1) / SCB;   // scan blocks (<=256)

    hipLaunchKernelGGL(conv_pad_kernel, dim3(512), dim3(256), 0, stream, x, xb, N, IN, INp);
    hipLaunchKernelGGL(wtrans_all_kernel, dim3(896), dim3(256), 0, stream,
                       W[0], W[1], W[2], W[3], wt1, wt2, wt3, wt4, IN);

    hipMemsetAsync(deg, 0, (size_t)N * 4, stream);
    hipLaunchKernelGGL(deg_count_kernel, dim3((Etot + 255) / 256), dim3(256), 0, stream,
                       ei, deg, E, Etot);
    hipLaunchKernelGGL(scan1_kernel, dim3(SB), dim3(256), 0, stream, deg, bsum, N);
    hipLaunchKernelGGL(scan2_kernel, dim3(1), dim3(256), 0, stream, bsum, bpref, SB,
                       &rowptr[N]);
    hipLaunchKernelGGL(scan3_kernel, dim3(SB), dim3(256), 0, stream, deg, bpref,
                       rowptr, cursor, N);
    hipLaunchKernelGGL(scatter_kernel, dim3((Etot + 255) / 256), dim3(256), 0, stream,
                       ei, cursor, csrc, E, Etot);
    hipLaunchKernelGGL(gstart_kernel, dim3((N + 255) / 256), dim3(256), 0, stream,
                       batch, gstart, N, G);

    const int grid256 = (N + 63) / 64;
    const int grid128 = (N + 127) / 128;
    const int gatgrid = (N + 3) / 4;

    hipLaunchKernelGGL((gemm_fused<256, 4, false>), dim3(grid256), dim3(256), 0, stream,
                       xb, nullptr, wt1, avs[0], avd[0], h, asrc, adst, N, INp);
    hipLaunchKernelGGL((gat_agg<4, 64, false>), dim3(gatgrid), dim3(256), 0, stream,
                       rowptr, csrc, h, asrc, adst, bi[0], ga[0], be[0], mu[0], va[0], x1,
                       nullptr, nullptr, nullptr, nullptr, nullptr, N);
    hipLaunchKernelGGL((gemm_fused<256, 4, false>), dim3(grid256), dim3(256), 0, stream,
                       x1, nullptr, wt2, avs[1], avd[1], h, asrc, adst, N, 256);
    hipLaunchKernelGGL((gat_agg<4, 64, false>), dim3(gatgrid), dim3(256), 0, stream,
                       rowptr, csrc, h, asrc, adst, bi[1], ga[1], be[1], mu[1], va[1], x2,
                       nullptr, nullptr, nullptr, nullptr, nullptr, N);
    hipLaunchKernelGGL((gemm_fused<256, 4, true>), dim3(grid256), dim3(256), 0, stream,
                       x1, x2, wt3, avs[2], avd[2], h, asrc, adst, N, 256);
    hipLaunchKernelGGL((gat_agg<4, 64, false>), dim3(gatgrid), dim3(256), 0, stream,
                       rowptr, csrc, h, asrc, adst, bi[2], ga[2], be[2], mu[2], va[2], x3,
                       nullptr, nullptr, nullptr, nullptr, nullptr, N);
    hipLaunchKernelGGL((gemm_fused<128, 1, false>), dim3(grid128), dim3(256), 0, stream,
                       x3, nullptr, wt4, avs[3], avd[3], h, asrc, adst, N, 256);
    hipLaunchKernelGGL((gat_agg<1, 128, true>), dim3(gatgrid), dim3(256), 0, stream,
                       rowptr, csrc, h, asrc, adst, bi[3], ga[3], be[3], mu[3], va[3], x4,
                       pw1, pb1, pw2, pb2, gate, N);

    hipLaunchKernelGGL(pool_kernel, dim3(G), dim3(128), 0, stream, x4, gate, gstart, out);
    hipLaunchKernelGGL(gfeat_kernel, dim3(G), dim3(64), 0, stream, gfeat, gw, gb, out);
}

// Round 8
// 561.634 us; speedup vs baseline: 6.6852x; 1.0358x over previous
//
#include <hip/hip_runtime.h>
#include <cstdint>
#include <cstddef>

#define NEG_SLOPE 0.2f
#define BN_EPS 1e-5f

typedef __bf16 bf16x8 __attribute__((ext_vector_type(8)));
typedef __bf16 bf16x4 __attribute__((ext_vector_type(4)));
typedef __bf16 bf16x2 __attribute__((ext_vector_type(2)));
typedef float  f32x4  __attribute__((ext_vector_type(4)));

// ---------- prep: x fp32 [N][K] -> bf16 [N][Kpad] zero-padded ----------
__global__ void conv_pad_kernel(const float* __restrict__ x, __bf16* __restrict__ xb,
                                int N, int K, int Kpad) {
    int i = blockIdx.x * blockDim.x + threadIdx.x;
    int total = N * Kpad;
    for (; i < total; i += gridDim.x * blockDim.x) {
        int n = i / Kpad, k = i - n * Kpad;
        xb[i] = (k < K) ? (__bf16)x[(size_t)n * K + k] : (__bf16)0.f;
    }
}

// ---------- prep: all 4 weight transposes in one launch ----------
__global__ void wtrans_all_kernel(const float* __restrict__ W1, const float* __restrict__ W2,
                                  const float* __restrict__ W3, const float* __restrict__ W4,
                                  __bf16* __restrict__ wt1, __bf16* __restrict__ wt2,
                                  __bf16* __restrict__ wt3, __bf16* __restrict__ wt4, int IN) {
    int b = blockIdx.x;
    const float* W; __bf16* WT; int K, D, Kpad, col;
    if (b < 256)      { W = W1; WT = wt1; K = IN;  D = 256; Kpad = 64;  col = b; }
    else if (b < 512) { W = W2; WT = wt2; K = 256; D = 256; Kpad = 256; col = b - 256; }
    else if (b < 768) { W = W3; WT = wt3; K = 256; D = 256; Kpad = 256; col = b - 512; }
    else              { W = W4; WT = wt4; K = 256; D = 128; Kpad = 256; col = b - 768; }
    for (int k = threadIdx.x; k < Kpad; k += blockDim.x)
        WT[(size_t)col * Kpad + k] = (k < K) ? (__bf16)W[(size_t)k * D + col] : (__bf16)0.f;
}

// ================= LDS-free MFMA GEMM strip + fused alpha =================
template<int DCOLS, int HEADS, bool HAS_A2>
__global__ __launch_bounds__(256) void gemm_fused(
    const __bf16* __restrict__ A, const __bf16* __restrict__ A2,
    const __bf16* __restrict__ WT,
    const float* __restrict__ asv, const float* __restrict__ adv,
    __bf16* __restrict__ H, float* __restrict__ alpha_s, float* __restrict__ alpha_d,
    int M, int K) {
    constexpr int RB = (DCOLS == 256) ? 64 : 128;
    const int w    = threadIdx.x >> 6;
    const int lane = threadIdx.x & 63;
    const int l16  = lane & 15, hi4 = lane >> 4;
    const int rg    = (DCOLS == 256) ? 0 : (w >> 1);
    const int ct    = (DCOLS == 256) ? w : (w & 1);
    const int col0w = ct * 64;
    const int rbase = rg * 64;
    const int n0 = blockIdx.x * RB;
    const int lk = hi4 * 8;

    f32x4 acc[4][4] = {};
    int arow[4];
    #pragma unroll
    for (int i = 0; i < 4; ++i) {
        int r = n0 + rbase + i * 16 + l16;
        arow[i] = (r < M) ? r : (M - 1);
    }

    for (int k0 = 0; k0 < K; k0 += 32) {
        bf16x8 af[4], bfr[4];
        #pragma unroll
        for (int i = 0; i < 4; ++i) {
            bf16x8 v = *(const bf16x8*)&A[(size_t)arow[i] * K + k0 + lk];
            if (HAS_A2) {
                bf16x8 v2 = *(const bf16x8*)&A2[(size_t)arow[i] * K + k0 + lk];
                #pragma unroll
                for (int j = 0; j < 8; ++j) v[j] = (__bf16)((float)v[j] + (float)v2[j]);
            }
            af[i] = v;
        }
        #pragma unroll
        for (int j = 0; j < 4; ++j)
            bfr[j] = *(const bf16x8*)&WT[(size_t)(col0w + j * 16 + l16) * K + k0 + lk];
        #pragma unroll
        for (int i = 0; i < 4; ++i)
            #pragma unroll
            for (int j = 0; j < 4; ++j)
                acc[i][j] = __builtin_amdgcn_mfma_f32_16x16x32_bf16(
                    af[i], bfr[j], acc[i][j], 0, 0, 0);
    }

    #pragma unroll
    for (int i = 0; i < 4; ++i)
        #pragma unroll
        for (int q = 0; q < 4; ++q) {
            int row = n0 + rbase + i * 16 + hi4 * 4 + q;
            if (row < M)
                #pragma unroll
                for (int j = 0; j < 4; ++j)
                    H[(size_t)row * DCOLS + col0w + j * 16 + l16] = (__bf16)acc[i][j][q];
        }

    float asc[4], adc[4];
    #pragma unroll
    for (int j = 0; j < 4; ++j) {
        int c = col0w + j * 16 + l16;
        asc[j] = asv[c]; adc[j] = adv[c];
    }
    __shared__ float as_l[128][2], ad_l[128][2];
    #pragma unroll
    for (int i = 0; i < 4; ++i)
        #pragma unroll
        for (int q = 0; q < 4; ++q) {
            float ps = 0.f, pd = 0.f;
            #pragma unroll
            for (int j = 0; j < 4; ++j) {
                float v = acc[i][j][q];
                ps = fmaf(v, asc[j], ps);
                pd = fmaf(v, adc[j], pd);
            }
            #pragma unroll
            for (int o = 1; o < 16; o <<= 1) {
                ps += __shfl_xor(ps, o, 64);
                pd += __shfl_xor(pd, o, 64);
            }
            int rl = rbase + i * 16 + hi4 * 4 + q;
            if constexpr (DCOLS == 256) {
                int row = n0 + rl;
                if (l16 == 0 && row < M) {
                    alpha_s[row * HEADS + w] = ps;
                    alpha_d[row * HEADS + w] = pd;
                }
            } else {
                if (l16 == 0) { as_l[rl][ct] = ps; ad_l[rl][ct] = pd; }
            }
        }
    if constexpr (DCOLS == 128) {
        __syncthreads();
        int t = threadIdx.x;
        if (t < 128) {
            int row = n0 + t;
            if (row < M) {
                alpha_s[row] = as_l[t][0] + as_l[t][1];
                alpha_d[row] = ad_l[t][0] + ad_l[t][1];
            }
        }
    }
}

// ================= CSR build (once per call) =================
__global__ void deg_count_kernel(const int* __restrict__ ei, int* __restrict__ deg,
                                 int E, int Etot) {
    int e = blockIdx.x * blockDim.x + threadIdx.x;
    if (e >= Etot) return;
    int d = (e < E) ? ei[E + e] : e - E;
    atomicAdd(&deg[d], 1);
}

// ---------- 3-phase multi-block exclusive scan of deg[N] ----------
#define SCB 4096
__global__ __launch_bounds__(256) void scan1_kernel(const int* __restrict__ deg,
                                                    int* __restrict__ bsum, int N) {
    __shared__ int ts[256];
    const int t = threadIdx.x;
    const int base = blockIdx.x * SCB + t * 16;
    int s = 0;
    #pragma unroll
    for (int i = 0; i < 16; ++i) {
        int idx = base + i;
        if (idx < N) s += deg[idx];
    }
    ts[t] = s;
    __syncthreads();
    for (int off = 128; off > 0; off >>= 1) {
        if (t < off) ts[t] += ts[t + off];
        __syncthreads();
    }
    if (t == 0) bsum[blockIdx.x] = ts[0];
}

__global__ __launch_bounds__(256) void scan2_kernel(const int* __restrict__ bsum,
                                                    int* __restrict__ bpref, int B,
                                                    int* __restrict__ rowptrN) {
    __shared__ int sm[256];
    const int t = threadIdx.x;
    int v = (t < B) ? bsum[t] : 0;
    sm[t] = v;
    __syncthreads();
    for (int off = 1; off < 256; off <<= 1) {
        int u = (t >= off) ? sm[t - off] : 0;
        __syncthreads();
        sm[t] += u;
        __syncthreads();
    }
    if (t < B) bpref[t] = sm[t] - v;
    if (t == 255) *rowptrN = sm[255];
}

__global__ __launch_bounds__(256) void scan3_kernel(const int* __restrict__ deg,
                                                    const int* __restrict__ bpref,
                                                    int* __restrict__ rowptr,
                                                    int* __restrict__ cursor, int N) {
    __shared__ int ts[256];
    const int t = threadIdx.x;
    const int base = blockIdx.x * SCB + t * 16;
    int d[16];
    int s = 0;
    #pragma unroll
    for (int i = 0; i < 16; ++i) {
        int idx = base + i;
        d[i] = (idx < N) ? deg[idx] : 0;
        s += d[i];
    }
    ts[t] = s;
    __syncthreads();
    for (int off = 1; off < 256; off <<= 1) {
        int u = (t >= off) ? ts[t - off] : 0;
        __syncthreads();
        ts[t] += u;
        __syncthreads();
    }
    int run = bpref[blockIdx.x] + ts[t] - s;
    #pragma unroll
    for (int i = 0; i < 16; ++i) {
        int idx = base + i;
        if (idx < N) { rowptr[idx] = run; cursor[idx] = run; run += d[i]; }
    }
}

__global__ void scatter_kernel(const int* __restrict__ ei, int* __restrict__ cursor,
                               int* __restrict__ csrc, int E, int Etot) {
    int e = blockIdx.x * blockDim.x + threadIdx.x;
    if (e >= Etot) return;
    int s, d;
    if (e < E) { s = ei[e]; d = ei[E + e]; } else { s = d = e - E; }
    int pos = atomicAdd(&cursor[d], 1);
    csrc[pos] = s;
}

__global__ void gstart_kernel(const int* __restrict__ batch, int* __restrict__ gstart,
                              int N, int G) {
    int n = blockIdx.x * blockDim.x + threadIdx.x;
    if (n >= N) return;
    int b = batch[n];
    if (n == 0) { for (int g = 0; g <= b; ++g) gstart[g] = 0; }
    else {
        int bp = batch[n - 1];
        for (int g = bp + 1; g <= b; ++g) gstart[g] = n;
    }
    if (n == N - 1) { for (int g = b + 1; g <= G; ++g) gstart[g] = N; }
}

// ============ wave-per-node GAT edge phase ============
template<int HEADS, int C, bool GATE>
__global__ __launch_bounds__(256) void gat_agg(
    const int* __restrict__ rowptr, const int* __restrict__ csrc,
    const __bf16* __restrict__ hf, const float* __restrict__ asrc,
    const float* __restrict__ adst,
    const float* __restrict__ bias, const float* __restrict__ gamma,
    const float* __restrict__ beta, const float* __restrict__ mean,
    const float* __restrict__ var,
    __bf16* __restrict__ out,
    const float* __restrict__ pw1, const float* __restrict__ pb1,
    const float* __restrict__ pw2, const float* __restrict__ pb2,
    float* __restrict__ gateout, int N) {
    constexpr int D = HEADS * C;
    constexpr int VPL = D / 64;
    using bvec = typename std::conditional<VPL == 4, bf16x4, bf16x2>::type;

    const int wid  = threadIdx.x >> 6;
    const int lane = threadIdx.x & 63;
    const int node = blockIdx.x * 4 + wid;

    __shared__ int   soff[4][64];
    __shared__ float pal[4][64][HEADS];
    __shared__ float x4row[4][128];
    __shared__ float pw1s[GATE ? 128 * 32 : 1];   // staged gate weights

    if constexpr (GATE) {
        for (int i = threadIdx.x; i < 128 * 32; i += 256) pw1s[i] = pw1[i];
        __syncthreads();
    }

    if (node < N) {
        const int beg = rowptr[node], end = rowptr[node + 1];
        const int deg = end - beg;
        const int c0 = lane * VPL;
        const int hd = c0 / C;
        const char* hb = (const char*)hf + (size_t)c0 * 2;

        float ad[HEADS];
        #pragma unroll
        for (int h = 0; h < HEADS; ++h) ad[h] = adst[node * HEADS + h];

        float accv[VPL] = {};

        if (deg <= 64) {
            const bool act = lane < deg;
            int msrc = act ? csrc[beg + lane] : 0;
            float lv[HEADS];
            if constexpr (HEADS == 4) {
                float4 a4 = ((const float4*)asrc)[msrc];
                lv[0] = a4.x; lv[1] = a4.y; lv[2] = a4.z; lv[3] = a4.w;
            } else {
                lv[0] = asrc[msrc];
            }
            float p[HEADS];
            #pragma unroll
            for (int h = 0; h < HEADS; ++h) {
                float v;
                if (act) { v = lv[h] + ad[h]; v = v > 0.f ? v : NEG_SLOPE * v; }
                else v = -INFINITY;
                float mx = v;
                #pragma unroll
                for (int o = 1; o < 64; o <<= 1) mx = fmaxf(mx, __shfl_xor(mx, o, 64));
                float pe = act ? __expf(v - mx) : 0.f;
                float ps = pe;
                #pragma unroll
                for (int o = 1; o < 64; o <<= 1) ps += __shfl_xor(ps, o, 64);
                p[h] = pe * (1.f / (ps + 1e-16f));
            }
            soff[wid][lane] = msrc * (D * 2);
            if constexpr (HEADS == 4)
                *(float4*)&pal[wid][lane][0] = make_float4(p[0], p[1], p[2], p[3]);
            else
                pal[wid][lane][0] = p[0];
            asm volatile("s_waitcnt lgkmcnt(0)" ::: "memory");

            // ---- aggregation: 8-deep unrolled gather for load ILP ----
            int e = 0;
            for (; e + 8 <= deg; e += 8) {
                int4 oa = *(const int4*)&soff[wid][e];
                int4 ob = *(const int4*)&soff[wid][e + 4];
                float q0 = pal[wid][e + 0][hd], q1 = pal[wid][e + 1][hd];
                float q2 = pal[wid][e + 2][hd], q3 = pal[wid][e + 3][hd];
                float q4 = pal[wid][e + 4][hd], q5 = pal[wid][e + 5][hd];
                float q6 = pal[wid][e + 6][hd], q7 = pal[wid][e + 7][hd];
                bvec v0 = *(const bvec*)(hb + oa.x);
                bvec v1 = *(const bvec*)(hb + oa.y);
                bvec v2 = *(const bvec*)(hb + oa.z);
                bvec v3 = *(const bvec*)(hb + oa.w);
                bvec v4 = *(const bvec*)(hb + ob.x);
                bvec v5 = *(const bvec*)(hb + ob.y);
                bvec v6 = *(const bvec*)(hb + ob.z);
                bvec v7 = *(const bvec*)(hb + ob.w);
                #pragma unroll
                for (int i = 0; i < VPL; ++i) {
                    accv[i] = fmaf((float)v0[i], q0, accv[i]);
                    accv[i] = fmaf((float)v1[i], q1, accv[i]);
                    accv[i] = fmaf((float)v2[i], q2, accv[i]);
                    accv[i] = fmaf((float)v3[i], q3, accv[i]);
                    accv[i] = fmaf((float)v4[i], q4, accv[i]);
                    accv[i] = fmaf((float)v5[i], q5, accv[i]);
                    accv[i] = fmaf((float)v6[i], q6, accv[i]);
                    accv[i] = fmaf((float)v7[i], q7, accv[i]);
                }
            }
            for (; e + 4 <= deg; e += 4) {
                int4 oa = *(const int4*)&soff[wid][e];
                float q0 = pal[wid][e + 0][hd], q1 = pal[wid][e + 1][hd];
                float q2 = pal[wid][e + 2][hd], q3 = pal[wid][e + 3][hd];
                bvec v0 = *(const bvec*)(hb + oa.x);
                bvec v1 = *(const bvec*)(hb + oa.y);
                bvec v2 = *(const bvec*)(hb + oa.z);
                bvec v3 = *(const bvec*)(hb + oa.w);
                #pragma unroll
                for (int i = 0; i < VPL; ++i) {
                    accv[i] = fmaf((float)v0[i], q0, accv[i]);
                    accv[i] = fmaf((float)v1[i], q1, accv[i]);
                    accv[i] = fmaf((float)v2[i], q2, accv[i]);
                    accv[i] = fmaf((float)v3[i], q3, accv[i]);
                }
            }
            for (; e < deg; ++e) {
                int o0 = soff[wid][e];
                float q0 = pal[wid][e][hd];
                bvec v0 = *(const bvec*)(hb + o0);
                #pragma unroll
                for (int i = 0; i < VPL; ++i)
                    accv[i] = fmaf((float)v0[i], q0, accv[i]);
            }
        } else {
            float mx[HEADS], sm[HEADS], inv[HEADS];
            #pragma unroll
            for (int h = 0; h < HEADS; ++h) mx[h] = -INFINITY;
            for (int j = beg + lane; j < end; j += 64) {
                int s = csrc[j];
                #pragma unroll
                for (int h = 0; h < HEADS; ++h) {
                    float v = asrc[s * HEADS + h] + ad[h];
                    v = v > 0.f ? v : NEG_SLOPE * v;
                    mx[h] = fmaxf(mx[h], v);
                }
            }
            #pragma unroll
            for (int h = 0; h < HEADS; ++h) {
                #pragma unroll
                for (int o = 1; o < 64; o <<= 1) mx[h] = fmaxf(mx[h], __shfl_xor(mx[h], o, 64));
                sm[h] = 0.f;
            }
            for (int j = beg + lane; j < end; j += 64) {
                int s = csrc[j];
                #pragma unroll
                for (int h = 0; h < HEADS; ++h) {
                    float v = asrc[s * HEADS + h] + ad[h];
                    v = v > 0.f ? v : NEG_SLOPE * v;
                    sm[h] += __expf(v - mx[h]);
                }
            }
            #pragma unroll
            for (int h = 0; h < HEADS; ++h) {
                #pragma unroll
                for (int o = 1; o < 64; o <<= 1) sm[h] += __shfl_xor(sm[h], o, 64);
                inv[h] = 1.f / (sm[h] + 1e-16f);
            }
            for (int base = beg; base < end; base += 64) {
                int ne = min(64, end - base);
                bool act = lane < ne;
                int msrc = act ? csrc[base + lane] : 0;
                soff[wid][lane] = msrc * (D * 2);
                #pragma unroll
                for (int h = 0; h < HEADS; ++h) {
                    float pv = 0.f;
                    if (act) {
                        float v = asrc[msrc * HEADS + h] + ad[h];
                        v = v > 0.f ? v : NEG_SLOPE * v;
                        pv = __expf(v - mx[h]) * inv[h];
                    }
                    pal[wid][lane][h] = pv;
                }
                asm volatile("s_waitcnt lgkmcnt(0)" ::: "memory");
                for (int e = 0; e < ne; ++e) {
                    int o0 = soff[wid][e];
                    float q0 = pal[wid][e][hd];
                    bvec v0 = *(const bvec*)(hb + o0);
                    #pragma unroll
                    for (int i = 0; i < VPL; ++i)
                        accv[i] = fmaf((float)v0[i], q0, accv[i]);
                }
                asm volatile("s_waitcnt lgkmcnt(0)" ::: "memory");
            }
        }

        // ---- epilogue: bias + BN(inference) + ReLU -> bf16 ----
        bvec ov;
        #pragma unroll
        for (int i = 0; i < VPL; ++i) {
            int c = c0 + i;
            float v = accv[i] + bias[c];
            v = (v - mean[c]) * rsqrtf(var[c] + BN_EPS) * gamma[c] + beta[c];
            v = fmaxf(v, 0.f);
            ov[i] = (__bf16)v;
            if constexpr (GATE) x4row[wid][c] = v;
        }
        *(bvec*)&out[(size_t)node * D + c0] = ov;

        if constexpr (GATE) {
            // gate = relu(x4row . pw1 + pb1) . pw2 + pb2, all 64 lanes:
            // lane = (hidden j = lane&31, cc-half = lane>>5); 64 FMAs each.
            asm volatile("s_waitcnt lgkmcnt(0)" ::: "memory");
            const int j = lane & 31;
            const int half = lane >> 5;
            float p = 0.f;
            const float* xr = &x4row[wid][half * 64];
            const float* pwb = &pw1s[half * 64 * 32 + j];
            #pragma unroll 16
            for (int cc = 0; cc < 64; ++cc)
                p = fmaf(xr[cc], pwb[cc * 32], p);
            p += __shfl_xor(p, 32, 64);           // combine cc-halves
            float g = fmaxf(p + pb1[j], 0.f) * pw2[j];
            #pragma unroll
            for (int o = 1; o < 32; o <<= 1) g += __shfl_xor(g, o, 64);
            if (lane == 0) gateout[node] = g + pb2[0];
        }
    }
}

// ---------- block-per-graph pooling ----------
__global__ __launch_bounds__(128) void pool_kernel(
    const __bf16* __restrict__ x4, const float* __restrict__ gate,
    const int* __restrict__ gstart, float* __restrict__ out) {
    const int g = blockIdx.x;
    const int t = threadIdx.x;
    const int beg = gstart[g], end = gstart[g + 1];
    __shared__ float red[128];
    __shared__ float wbuf[128];
    float m = -INFINITY;
    for (int n = beg + t; n < end; n += 128) m = fmaxf(m, gate[n]);
    red[t] = m; __syncthreads();
    for (int off = 64; off > 0; off >>= 1) {
        if (t < off) red[t] = fmaxf(red[t], red[t + off]);
        __syncthreads();
    }
    m = red[0]; __syncthreads();
    float s = 0.f;
    for (int n = beg + t; n < end; n += 128) s += expf(gate[n] - m);
    red[t] = s; __syncthreads();
    for (int off = 64; off > 0; off >>= 1) {
        if (t < off) red[t] += red[t + off];
        __syncthreads();
    }
    const float inv = 1.f / (red[0] + 1e-16f);
    __syncthreads();
    float acc = 0.f;
    for (int base = beg; base < end; base += 128) {
        int ne = min(128, end - base);
        if (t < ne) wbuf[t] = expf(gate[base + t] - m) * inv;
        __syncthreads();
        for (int i = 0; i < ne; ++i)
            acc = fmaf(wbuf[i], (float)x4[(size_t)(base + i) * 128 + t], acc);
        __syncthreads();
    }
    out[(size_t)g * 160 + t] = acc;
}

// ---------- global-feature MLP into d_out[:, 128:160] ----------
__global__ void gfeat_kernel(const float* __restrict__ gfeat,
                             const float* __restrict__ gw, const float* __restrict__ gb,
                             float* __restrict__ out) {
    const int g = blockIdx.x;
    const int k = threadIdx.x;
    if (k < 32) {
        float t = gb[k];
        #pragma unroll
        for (int j = 0; j < 7; ++j) t = fmaf(gfeat[g * 7 + j], gw[j * 32 + k], t);
        out[(size_t)g * 160 + 128 + k] = fmaxf(t, 0.f);
    }
}

// ==========================================================================
extern "C" void kernel_launch(void* const* d_in, const int* in_sizes, int n_in,
                              void* d_out, int out_size, void* d_ws, size_t ws_size,
                              hipStream_t stream) {
    const float* x      = (const float*)d_in[0];
    const int*   ei     = (const int*)  d_in[1];
    const int*   batch  = (const int*)  d_in[2];
    const float* gfeat  = (const float*)d_in[3];

    const int N    = in_sizes[2];
    const int E    = in_sizes[1] / 2;
    const int G    = in_sizes[3] / 7;
    const int IN   = in_sizes[0] / N;
    const int Etot = E + N;
    const int INp  = 64;

    const float* W[4];  const float* avs[4]; const float* avd[4]; const float* bi[4];
    const float* ga[4]; const float* be[4];  const float* mu[4];  const float* va[4];
    for (int l = 0; l < 4; ++l) {
        int o = 4 + 8 * l;
        W[l]   = (const float*)d_in[o + 0];
        avs[l] = (const float*)d_in[o + 1];
        avd[l] = (const float*)d_in[o + 2];
        bi[l]  = (const float*)d_in[o + 3];
        ga[l]  = (const float*)d_in[o + 4];
        be[l]  = (const float*)d_in[o + 5];
        mu[l]  = (const float*)d_in[o + 6];
        va[l]  = (const float*)d_in[o + 7];
    }
    const float* pw1 = (const float*)d_in[36];
    const float* pb1 = (const float*)d_in[37];
    const float* pw2 = (const float*)d_in[38];
    const float* pb2 = (const float*)d_in[39];
    const float* gw  = (const float*)d_in[40];
    const float* gb  = (const float*)d_in[41];

    float* out = (float*)d_out;

    float* ws = (float*)d_ws;
    __bf16* xb = (__bf16*)ws; ws += (size_t)N * 32;
    __bf16* h  = (__bf16*)ws; ws += (size_t)N * 128;
    __bf16* x1 = (__bf16*)ws; ws += (size_t)N * 128;
    __bf16* x2 = (__bf16*)ws; ws += (size_t)N * 128;
    __bf16* x3 = (__bf16*)ws; ws += (size_t)N * 128;
    __bf16* wt1 = (__bf16*)ws; ws += 256 * 64 / 2;
    __bf16* wt2 = (__bf16*)ws; ws += 256 * 256 / 2;
    __bf16* wt3 = (__bf16*)ws; ws += 256 * 256 / 2;
    __bf16* wt4 = (__bf16*)ws; ws += 128 * 256 / 2;
    float* asrc = ws;  ws += (size_t)N * 4;
    float* adst = ws;  ws += (size_t)N * 4;
    float* gate = ws;  ws += N;
    int* deg    = (int*)ws; ws += N;
    int* cursor = (int*)ws; ws += N;
    int* rowptr = (int*)ws; ws += (N + 1);
    int* csrc   = (int*)ws; ws += Etot;
    int* gstart = (int*)ws; ws += (G + 1);
    int* bsum   = (int*)ws; ws += 256;
    int* bpref  = (int*)ws; ws += 256;
    __bf16* x4 = x1;

    const int SB = (N + SCB - 1) / SCB;

    hipLaunchKernelGGL(conv_pad_kernel, dim3(512), dim3(256), 0, stream, x, xb, N, IN, INp);
    hipLaunchKernelGGL(wtrans_all_kernel, dim3(896), dim3(256), 0, stream,
                       W[0], W[1], W[2], W[3], wt1, wt2, wt3, wt4, IN);

    hipMemsetAsync(deg, 0, (size_t)N * 4, stream);
    hipLaunchKernelGGL(deg_count_kernel, dim3((Etot + 255) / 256), dim3(256), 0, stream,
                       ei, deg, E, Etot);
    hipLaunchKernelGGL(scan1_kernel, dim3(SB), dim3(256), 0, stream, deg, bsum, N);
    hipLaunchKernelGGL(scan2_kernel, dim3(1), dim3(256), 0, stream, bsum, bpref, SB,
                       &rowptr[N]);
    hipLaunchKernelGGL(scan3_kernel, dim3(SB), dim3(256), 0, stream, deg, bpref,
                       rowptr, cursor, N);
    hipLaunchKernelGGL(scatter_kernel, dim3((Etot + 255) / 256), dim3(256), 0, stream,
                       ei, cursor, csrc, E, Etot);
    hipLaunchKernelGGL(gstart_kernel, dim3((N + 255) / 256), dim3(256), 0, stream,
                       batch, gstart, N, G);

    const int grid256 = (N + 63) / 64;
    const int grid128 = (N + 127) / 128;
    const int gatgrid = (N + 3) / 4;

    hipLaunchKernelGGL((gemm_fused<256, 4, false>), dim3(grid256), dim3(256), 0, stream,
                       xb, nullptr, wt1, avs[0], avd[0], h, asrc, adst, N, INp);
    hipLaunchKernelGGL((gat_agg<4, 64, false>), dim3(gatgrid), dim3(256), 0, stream,
                       rowptr, csrc, h, asrc, adst, bi[0], ga[0], be[0], mu[0], va[0], x1,
                       nullptr, nullptr, nullptr, nullptr, nullptr, N);
    hipLaunchKernelGGL((gemm_fused<256, 4, false>), dim3(grid256), dim3(256), 0, stream,
                       x1, nullptr, wt2, avs[1], avd[1], h, asrc, adst, N, 256);
    hipLaunchKernelGGL((gat_agg<4, 64, false>), dim3(gatgrid), dim3(256), 0, stream,
                       rowptr, csrc, h, asrc, adst, bi[1], ga[1], be[1], mu[1], va[1], x2,
                       nullptr, nullptr, nullptr, nullptr, nullptr, N);
    hipLaunchKernelGGL((gemm_fused<256, 4, true>), dim3(grid256), dim3(256), 0, stream,
                       x1, x2, wt3, avs[2], avd[2], h, asrc, adst, N, 256);
    hipLaunchKernelGGL((gat_agg<4, 64, false>), dim3(gatgrid), dim3(256), 0, stream,
                       rowptr, csrc, h, asrc, adst, bi[2], ga[2], be[2], mu[2], va[2], x3,
                       nullptr, nullptr, nullptr, nullptr, nullptr, N);
    hipLaunchKernelGGL((gemm_fused<128, 1, false>), dim3(grid128), dim3(256), 0, stream,
                       x3, nullptr, wt4, avs[3], avd[3], h, asrc, adst, N, 256);
    hipLaunchKernelGGL((gat_agg<1, 128, true>), dim3(gatgrid), dim3(256), 0, stream,
                       rowptr, csrc, h, asrc, adst, bi[3], ga[3], be[3], mu[3], va[3], x4,
                       pw1, pb1, pw2, pb2, gate, N);

    hipLaunchKernelGGL(pool_kernel, dim3(G), dim3(128), 0, stream, x4, gate, gstart, out);
    hipLaunchKernelGGL(gfeat_kernel, dim3(G), dim3(64), 0, stream, gfeat, gw, gb, out);
}